// Round 1
// baseline (1569.503 us; speedup 1.0000x reference)
//
#include <hip/hip_runtime.h>

#define DIN 256
#define DH  256
#define DOUT 128

// ---------------- degree ----------------
__global__ void deg_kernel(const int* __restrict__ dst, float* __restrict__ deg, int E) {
    int e = blockIdx.x * blockDim.x + threadIdx.x;
    if (e < E) atomicAdd(&deg[dst[e]], 1.0f);
}

// ---------------- edge scatter-add: one wave per edge ----------------
template<int D>
__global__ void scatter_kernel(const float* __restrict__ p, const int* __restrict__ src,
                               const int* __restrict__ dst, float* __restrict__ agg, int E) {
    int wid  = (int)((blockIdx.x * (long long)blockDim.x + threadIdx.x) >> 6);
    int lane = threadIdx.x & 63;
    if (wid >= E) return;
    int s = src[wid], d = dst[wid];
    const float* ps = p   + (long long)s * D;
    float*       ad = agg + (long long)d * D;
#pragma unroll
    for (int j = 0; j < D / 64; ++j)
        atomicAdd(&ad[lane + 64 * j], ps[lane + 64 * j]);
}

// ---------------- fused GEMM ----------------
// C[M x Nc] = act( A@W  (+ (A2/max(deg2,1))@W2)  (+ addend/max(adeg,1))  + bias )
__global__ __launch_bounds__(256)
void gemm_kernel(const float* __restrict__ A,  const float* __restrict__ W,
                 const float* __restrict__ A2, const float* __restrict__ W2,
                 const float* __restrict__ deg2,
                 const float* __restrict__ addend, const float* __restrict__ adeg,
                 const float* __restrict__ bias,
                 float* __restrict__ C,
                 int M, int K, int Nc, int do_relu)
{
    __shared__ float As[16][68];   // [k][row], padded for b128-aligned reads
    __shared__ float Ws[16][64];   // [k][col]

    const int tid = threadIdx.x;
    const int tx = tid & 15, ty = tid >> 4;
    const int row0 = blockIdx.x * 64;
    const int col0 = blockIdx.y * 64;

    float acc[4][4] = {};

    for (int pass = 0; pass < 2; ++pass) {
        if (pass == 1 && A2 == nullptr) break;
        const float* Ap = pass ? A2 : A;
        const float* Wp = pass ? W2 : W;
        for (int k0 = 0; k0 < K; k0 += 16) {
            // stage A: 64 rows x 16 k (float4 per thread)
            {
                int r  = tid >> 2;            // 0..63
                int kq = (tid & 3) << 2;      // 0,4,8,12
                int grow = row0 + r;
                float4 v = make_float4(0.f, 0.f, 0.f, 0.f);
                if (grow < M) {
                    v = *(const float4*)(Ap + (long long)grow * K + k0 + kq);
                    if (pass && deg2) {
                        float inv = 1.0f / fmaxf(deg2[grow], 1.0f);
                        v.x *= inv; v.y *= inv; v.z *= inv; v.w *= inv;
                    }
                }
                As[kq + 0][r] = v.x; As[kq + 1][r] = v.y;
                As[kq + 2][r] = v.z; As[kq + 3][r] = v.w;
            }
            // stage W: 16 k x 64 cols (float4 per thread)
            {
                int kr = tid >> 4;            // 0..15
                int cq = (tid & 15) << 2;     // 0..60
                *(float4*)&Ws[kr][cq] =
                    *(const float4*)(Wp + (long long)(k0 + kr) * Nc + col0 + cq);
            }
            __syncthreads();
#pragma unroll
            for (int k = 0; k < 16; ++k) {
                float4 av = *(const float4*)&As[k][ty * 4];
                float4 bv = *(const float4*)&Ws[k][tx * 4];
                float a[4] = {av.x, av.y, av.z, av.w};
                float b[4] = {bv.x, bv.y, bv.z, bv.w};
#pragma unroll
                for (int i = 0; i < 4; ++i)
#pragma unroll
                    for (int j = 0; j < 4; ++j)
                        acc[i][j] += a[i] * b[j];
            }
            __syncthreads();
        }
    }

    // epilogue
#pragma unroll
    for (int i = 0; i < 4; ++i) {
        int grow = row0 + ty * 4 + i;
        if (grow >= M) continue;
        int gcol = col0 + tx * 4;
        float4 v = make_float4(acc[i][0], acc[i][1], acc[i][2], acc[i][3]);
        if (addend) {
            float inv = 1.0f / fmaxf(adeg[grow], 1.0f);
            const float* ad = addend + (long long)grow * Nc + gcol;
            v.x += ad[0] * inv; v.y += ad[1] * inv;
            v.z += ad[2] * inv; v.w += ad[3] * inv;
        }
        if (bias) {
            v.x += bias[gcol + 0]; v.y += bias[gcol + 1];
            v.z += bias[gcol + 2]; v.w += bias[gcol + 3];
        }
        if (do_relu) {
            v.x = fmaxf(v.x, 0.f); v.y = fmaxf(v.y, 0.f);
            v.z = fmaxf(v.z, 0.f); v.w = fmaxf(v.w, 0.f);
        }
        *(float4*)(C + (long long)grow * Nc + gcol) = v;
    }
}

// ---------------- row L2-normalize (in place), one wave per row ----------------
__global__ void normalize_kernel(float* __restrict__ out, int N) {
    int wid  = (int)((blockIdx.x * (long long)blockDim.x + threadIdx.x) >> 6);
    int lane = threadIdx.x & 63;
    if (wid >= N) return;
    float* row = out + (long long)wid * DOUT;
    float a = row[lane], b = row[lane + 64];
    float ss = a * a + b * b;
#pragma unroll
    for (int off = 32; off; off >>= 1) ss += __shfl_xor(ss, off);
    float inv = 1.0f / fmaxf(sqrtf(ss), 1e-12f);
    row[lane] = a * inv; row[lane + 64] = b * inv;
}

extern "C" void kernel_launch(void* const* d_in, const int* in_sizes, int n_in,
                              void* d_out, int out_size, void* d_ws, size_t ws_size,
                              hipStream_t stream) {
    const float* feat     = (const float*)d_in[0];
    const int*   src      = (const int*)  d_in[1];
    const int*   dst      = (const int*)  d_in[2];
    const float* w_self1  = (const float*)d_in[3];
    const float* w_neigh1 = (const float*)d_in[4];
    const float* b1       = (const float*)d_in[5];
    const float* w_self2  = (const float*)d_in[6];
    const float* w_neigh2 = (const float*)d_in[7];
    const float* b2       = (const float*)d_in[8];
    float* out = (float*)d_out;

    const int N = in_sizes[0] / DIN;    // 100000
    const int E = in_sizes[1];          // 800000

    char* ws = (char*)d_ws;
    size_t degBytes = ((size_t)N * 4 + 4095) & ~(size_t)4095;
    float* deg = (float*)ws;                                        // N
    float* agg = (float*)(ws + degBytes);                           // N*256 (reused N*128 for s2)
    float* h1  = (float*)(ws + degBytes + (size_t)N * DIN * 4);     // N*256

    // zero deg + agg
    hipMemsetAsync(ws, 0, degBytes + (size_t)N * DIN * 4, stream);

    // in-degrees
    deg_kernel<<<(E + 255) / 256, 256, 0, stream>>>(dst, deg, E);

    // layer-1 neighbor sum: agg = segment_sum(feat[src], dst)
    scatter_kernel<DIN><<<(E + 3) / 4, 256, 0, stream>>>(feat, src, dst, agg, E);

    // h1 = relu(feat@w_self1 + (agg/deg)@w_neigh1 + b1)
    gemm_kernel<<<dim3((N + 63) / 64, DH / 64), 256, 0, stream>>>(
        feat, w_self1, agg, w_neigh1, deg, nullptr, nullptr, b1, h1, N, DIN, DH, 1);

    // p2 = h1 @ w_neigh2  (staged in d_out)
    gemm_kernel<<<dim3((N + 63) / 64, DOUT / 64), 256, 0, stream>>>(
        h1, w_neigh2, nullptr, nullptr, nullptr, nullptr, nullptr, nullptr, out, N, DH, DOUT, 0);

    // s2 = segment_sum(p2[src], dst)  (reuse agg)
    hipMemsetAsync(agg, 0, (size_t)N * DOUT * 4, stream);
    scatter_kernel<DOUT><<<(E + 3) / 4, 256, 0, stream>>>(out, src, dst, agg, E);

    // out = relu(h1@w_self2 + s2/deg + b2)
    gemm_kernel<<<dim3((N + 63) / 64, DOUT / 64), 256, 0, stream>>>(
        h1, w_self2, nullptr, nullptr, nullptr, agg, deg, b2, out, N, DH, DOUT, 1);

    // row L2 normalize
    normalize_kernel<<<(N + 3) / 4, 256, 0, stream>>>(out, N);
}

// Round 2
// 819.587 us; speedup vs baseline: 1.9150x; 1.9150x over previous
//
#include <hip/hip_runtime.h>

#define DIN 256
#define DH  256
#define DOUT 128

// ================= CSR build =================
__global__ void count_kernel(const int* __restrict__ dst, int* __restrict__ cnt, int E) {
    int e = blockIdx.x * blockDim.x + threadIdx.x;
    if (e < E) atomicAdd(&cnt[dst[e]], 1);
}

// 1024 elements per block, 256 threads x 4
__global__ void block_sums_kernel(const int* __restrict__ cnt, int* __restrict__ partial, int N) {
    __shared__ int sdata[256];
    int t = threadIdx.x;
    int base = blockIdx.x * 1024;
    int s = 0;
#pragma unroll
    for (int j = 0; j < 4; ++j) {
        int i = base + t * 4 + j;
        if (i < N) s += cnt[i];
    }
    sdata[t] = s; __syncthreads();
    for (int o = 128; o; o >>= 1) {
        if (t < o) sdata[t] += sdata[t + o];
        __syncthreads();
    }
    if (t == 0) partial[blockIdx.x] = sdata[0];
}

// single block: exclusive scan of nb (<=256) partials
__global__ void scan_partials_kernel(int* __restrict__ partial, int nb) {
    __shared__ int sdata[256];
    int t = threadIdx.x;
    int v = (t < nb) ? partial[t] : 0;
    sdata[t] = v; __syncthreads();
    for (int o = 1; o < 256; o <<= 1) {
        int y = (t >= o) ? sdata[t - o] : 0;
        __syncthreads();
        sdata[t] += y;
        __syncthreads();
    }
    if (t < nb) partial[t] = sdata[t] - v;   // exclusive
}

__global__ void scan_block_kernel(const int* __restrict__ cnt, const int* __restrict__ partial,
                                  int* __restrict__ off, int N, int E) {
    __shared__ int sdata[256];
    int b = blockIdx.x, t = threadIdx.x;
    int base = b * 1024;
    int vals[4]; int local = 0;
#pragma unroll
    for (int j = 0; j < 4; ++j) {
        int i = base + t * 4 + j;
        vals[j] = (i < N) ? cnt[i] : 0;
        local += vals[j];
    }
    sdata[t] = local; __syncthreads();
    for (int o = 1; o < 256; o <<= 1) {
        int y = (t >= o) ? sdata[t - o] : 0;
        __syncthreads();
        sdata[t] += y;
        __syncthreads();
    }
    int run = sdata[t] - local + partial[b];
#pragma unroll
    for (int j = 0; j < 4; ++j) {
        int i = base + t * 4 + j;
        if (i < N) off[i] = run;
        run += vals[j];
    }
    if (b == 0 && t == 0) off[N] = E;
}

__global__ void init_cursor_kernel(const int* __restrict__ off, int* __restrict__ cursor, int N) {
    int i = blockIdx.x * blockDim.x + threadIdx.x;
    if (i < N) cursor[i] = off[i];
}

__global__ void fill_csr_kernel(const int* __restrict__ src, const int* __restrict__ dst,
                                int* __restrict__ cursor, int* __restrict__ csr, int E) {
    int e = blockIdx.x * blockDim.x + threadIdx.x;
    if (e < E) {
        int d = dst[e];
        int p = atomicAdd(&cursor[d], 1);
        csr[p] = src[e];
    }
}

// ================= gather-mean (one wave per node) =================
__global__ void gather_mean256_kernel(const float* __restrict__ p, const int* __restrict__ off,
                                      const int* __restrict__ csr, float* __restrict__ agg, int N) {
    int wid  = (int)((blockIdx.x * (long long)blockDim.x + threadIdx.x) >> 6);
    int lane = threadIdx.x & 63;
    if (wid >= N) return;
    int start = off[wid], end = off[wid + 1];
    float4 acc = make_float4(0.f, 0.f, 0.f, 0.f);
    int e = start;
    for (; e + 3 < end; e += 4) {
        int s0 = csr[e], s1 = csr[e + 1], s2 = csr[e + 2], s3 = csr[e + 3];
        float4 v0 = *(const float4*)(p + (long long)s0 * 256 + lane * 4);
        float4 v1 = *(const float4*)(p + (long long)s1 * 256 + lane * 4);
        float4 v2 = *(const float4*)(p + (long long)s2 * 256 + lane * 4);
        float4 v3 = *(const float4*)(p + (long long)s3 * 256 + lane * 4);
        acc.x += v0.x + v1.x + v2.x + v3.x;
        acc.y += v0.y + v1.y + v2.y + v3.y;
        acc.z += v0.z + v1.z + v2.z + v3.z;
        acc.w += v0.w + v1.w + v2.w + v3.w;
    }
    for (; e < end; ++e) {
        int s = csr[e];
        float4 v = *(const float4*)(p + (long long)s * 256 + lane * 4);
        acc.x += v.x; acc.y += v.y; acc.z += v.z; acc.w += v.w;
    }
    float inv = 1.0f / (float)max(end - start, 1);
    acc.x *= inv; acc.y *= inv; acc.z *= inv; acc.w *= inv;
    *(float4*)(agg + (long long)wid * 256 + lane * 4) = acc;
}

__global__ void gather_mean128_kernel(const float* __restrict__ p, const int* __restrict__ off,
                                      const int* __restrict__ csr, float* __restrict__ agg, int N) {
    int wid  = (int)((blockIdx.x * (long long)blockDim.x + threadIdx.x) >> 6);
    int lane = threadIdx.x & 63;
    if (wid >= N) return;
    int start = off[wid], end = off[wid + 1];
    float2 acc = make_float2(0.f, 0.f);
    int e = start;
    for (; e + 3 < end; e += 4) {
        int s0 = csr[e], s1 = csr[e + 1], s2 = csr[e + 2], s3 = csr[e + 3];
        float2 v0 = *(const float2*)(p + (long long)s0 * 128 + lane * 2);
        float2 v1 = *(const float2*)(p + (long long)s1 * 128 + lane * 2);
        float2 v2 = *(const float2*)(p + (long long)s2 * 128 + lane * 2);
        float2 v3 = *(const float2*)(p + (long long)s3 * 128 + lane * 2);
        acc.x += v0.x + v1.x + v2.x + v3.x;
        acc.y += v0.y + v1.y + v2.y + v3.y;
    }
    for (; e < end; ++e) {
        int s = csr[e];
        float2 v = *(const float2*)(p + (long long)s * 128 + lane * 2);
        acc.x += v.x; acc.y += v.y;
    }
    float inv = 1.0f / (float)max(end - start, 1);
    acc.x *= inv; acc.y *= inv;
    *(float2*)(agg + (long long)wid * 128 + lane * 2) = acc;
}

// ================= fused GEMM =================
// C[M x Nc] = act( A@W (+ A2@W2) (+ addend) + bias )
__global__ __launch_bounds__(256)
void gemm_kernel(const float* __restrict__ A,  const float* __restrict__ W,
                 const float* __restrict__ A2, const float* __restrict__ W2,
                 const float* __restrict__ addend, const float* __restrict__ bias,
                 float* __restrict__ C,
                 int M, int K, int Nc, int do_relu)
{
    __shared__ float As[16][68];
    __shared__ float Ws[16][64];

    const int tid = threadIdx.x;
    const int tx = tid & 15, ty = tid >> 4;
    const int row0 = blockIdx.x * 64;
    const int col0 = blockIdx.y * 64;

    float acc[4][4] = {};

    for (int pass = 0; pass < 2; ++pass) {
        if (pass == 1 && A2 == nullptr) break;
        const float* Ap = pass ? A2 : A;
        const float* Wp = pass ? W2 : W;
        for (int k0 = 0; k0 < K; k0 += 16) {
            {
                int r  = tid >> 2;
                int kq = (tid & 3) << 2;
                int grow = row0 + r;
                float4 v = make_float4(0.f, 0.f, 0.f, 0.f);
                if (grow < M)
                    v = *(const float4*)(Ap + (long long)grow * K + k0 + kq);
                As[kq + 0][r] = v.x; As[kq + 1][r] = v.y;
                As[kq + 2][r] = v.z; As[kq + 3][r] = v.w;
            }
            {
                int kr = tid >> 4;
                int cq = (tid & 15) << 2;
                *(float4*)&Ws[kr][cq] =
                    *(const float4*)(Wp + (long long)(k0 + kr) * Nc + col0 + cq);
            }
            __syncthreads();
#pragma unroll
            for (int k = 0; k < 16; ++k) {
                float4 av = *(const float4*)&As[k][ty * 4];
                float4 bv = *(const float4*)&Ws[k][tx * 4];
                float a[4] = {av.x, av.y, av.z, av.w};
                float b[4] = {bv.x, bv.y, bv.z, bv.w};
#pragma unroll
                for (int i = 0; i < 4; ++i)
#pragma unroll
                    for (int j = 0; j < 4; ++j)
                        acc[i][j] += a[i] * b[j];
            }
            __syncthreads();
        }
    }

#pragma unroll
    for (int i = 0; i < 4; ++i) {
        int grow = row0 + ty * 4 + i;
        if (grow >= M) continue;
        int gcol = col0 + tx * 4;
        float4 v = make_float4(acc[i][0], acc[i][1], acc[i][2], acc[i][3]);
        if (addend) {
            const float* ad = addend + (long long)grow * Nc + gcol;
            v.x += ad[0]; v.y += ad[1]; v.z += ad[2]; v.w += ad[3];
        }
        if (bias) {
            v.x += bias[gcol + 0]; v.y += bias[gcol + 1];
            v.z += bias[gcol + 2]; v.w += bias[gcol + 3];
        }
        if (do_relu) {
            v.x = fmaxf(v.x, 0.f); v.y = fmaxf(v.y, 0.f);
            v.z = fmaxf(v.z, 0.f); v.w = fmaxf(v.w, 0.f);
        }
        *(float4*)(C + (long long)grow * Nc + gcol) = v;
    }
}

// ================= row L2-normalize =================
__global__ void normalize_kernel(float* __restrict__ out, int N) {
    int wid  = (int)((blockIdx.x * (long long)blockDim.x + threadIdx.x) >> 6);
    int lane = threadIdx.x & 63;
    if (wid >= N) return;
    float* row = out + (long long)wid * DOUT;
    float a = row[lane], b = row[lane + 64];
    float ss = a * a + b * b;
#pragma unroll
    for (int off = 32; off; off >>= 1) ss += __shfl_xor(ss, off);
    float inv = 1.0f / fmaxf(sqrtf(ss), 1e-12f);
    row[lane] = a * inv; row[lane + 64] = b * inv;
}

extern "C" void kernel_launch(void* const* d_in, const int* in_sizes, int n_in,
                              void* d_out, int out_size, void* d_ws, size_t ws_size,
                              hipStream_t stream) {
    const float* feat     = (const float*)d_in[0];
    const int*   src      = (const int*)  d_in[1];
    const int*   dst      = (const int*)  d_in[2];
    const float* w_self1  = (const float*)d_in[3];
    const float* w_neigh1 = (const float*)d_in[4];
    const float* b1       = (const float*)d_in[5];
    const float* w_self2  = (const float*)d_in[6];
    const float* w_neigh2 = (const float*)d_in[7];
    const float* b2       = (const float*)d_in[8];
    float* out = (float*)d_out;

    const int N = in_sizes[0] / DIN;    // 100000
    const int E = in_sizes[1];          // 800000

    char* ws = (char*)d_ws;
    auto align4k = [](size_t x) { return (x + 4095) & ~(size_t)4095; };
    size_t o = 0;
    int* cnt    = (int*)(ws + o); o += align4k((size_t)N * 4);         // counts, reused as cursor
    int* off    = (int*)(ws + o); o += align4k((size_t)(N + 1) * 4);
    int* part   = (int*)(ws + o); o += align4k(256 * 4);
    int* csr    = (int*)(ws + o); o += align4k((size_t)E * 4);
    float* agg  = (float*)(ws + o); o += (size_t)N * DIN * 4;          // N*256, reused N*128
    float* h1   = (float*)(ws + o); o += (size_t)N * DH * 4;

    const int nblk = (N + 1023) / 1024;   // 98

    // ---- CSR build ----
    hipMemsetAsync(cnt, 0, (size_t)N * 4, stream);
    count_kernel<<<(E + 255) / 256, 256, 0, stream>>>(dst, cnt, E);
    block_sums_kernel<<<nblk, 256, 0, stream>>>(cnt, part, N);
    scan_partials_kernel<<<1, 256, 0, stream>>>(part, nblk);
    scan_block_kernel<<<nblk, 256, 0, stream>>>(cnt, part, off, N, E);
    init_cursor_kernel<<<(N + 255) / 256, 256, 0, stream>>>(off, cnt, N);  // cnt becomes cursor
    fill_csr_kernel<<<(E + 255) / 256, 256, 0, stream>>>(src, dst, cnt, csr, E);

    // ---- layer 1 ----
    gather_mean256_kernel<<<(N + 3) / 4, 256, 0, stream>>>(feat, off, csr, agg, N);
    gemm_kernel<<<dim3((N + 63) / 64, DH / 64), 256, 0, stream>>>(
        feat, w_self1, agg, w_neigh1, nullptr, b1, h1, N, DIN, DH, 1);

    // ---- layer 2 ----
    // p2 = h1 @ w_neigh2 (staged in d_out)
    gemm_kernel<<<dim3((N + 63) / 64, DOUT / 64), 256, 0, stream>>>(
        h1, w_neigh2, nullptr, nullptr, nullptr, nullptr, out, N, DH, DOUT, 0);
    // agg2 = mean of p2 over in-neighbors (reuse agg)
    gather_mean128_kernel<<<(N + 3) / 4, 256, 0, stream>>>(out, off, csr, agg, N);
    // out = relu(h1@w_self2 + agg2 + b2)
    gemm_kernel<<<dim3((N + 63) / 64, DOUT / 64), 256, 0, stream>>>(
        h1, w_self2, nullptr, nullptr, agg, b2, out, N, DH, DOUT, 1);

    // ---- normalize ----
    normalize_kernel<<<(N + 3) / 4, 256, 0, stream>>>(out, N);
}

// Round 3
// 451.484 us; speedup vs baseline: 3.4763x; 1.8153x over previous
//
#include <hip/hip_runtime.h>

#define DIN 256
#define DH  256
#define DOUT 128

typedef __attribute__((ext_vector_type(8))) short bf16x8;
typedef __attribute__((ext_vector_type(4))) float f32x4;
typedef __attribute__((ext_vector_type(2))) unsigned short ushort2v;
typedef __attribute__((ext_vector_type(4))) unsigned short ushort4v;
typedef __attribute__((ext_vector_type(8))) unsigned short ushort8v;

static __device__ __forceinline__ unsigned short f2bf(float x) {
    unsigned u = __float_as_uint(x);
    u += 0x7fffu + ((u >> 16) & 1u);          // round-to-nearest-even
    return (unsigned short)(u >> 16);
}
static __device__ __forceinline__ float bf2f(unsigned short h) {
    return __uint_as_float(((unsigned)h) << 16);
}

// ================= converts =================
__global__ void cvt_bf16_kernel(const float* __restrict__ x, unsigned short* __restrict__ y, long long n8) {
    long long i = blockIdx.x * 256LL + threadIdx.x;
    if (i >= n8) return;
    const float4* p = (const float4*)(x + i * 8);
    float4 a = p[0], b = p[1];
    ushort8v o;
    o[0] = f2bf(a.x); o[1] = f2bf(a.y); o[2] = f2bf(a.z); o[3] = f2bf(a.w);
    o[4] = f2bf(b.x); o[5] = f2bf(b.y); o[6] = f2bf(b.z); o[7] = f2bf(b.w);
    *(ushort8v*)(y + i * 8) = o;
}

// wt[n][k] = bf16(w[k][n])
__global__ void wtrans_kernel(const float* __restrict__ w, unsigned short* __restrict__ wt, int K, int Ncols) {
    int idx = blockIdx.x * 256 + threadIdx.x;
    if (idx >= K * Ncols) return;
    int nn = idx / K, k = idx - nn * K;
    wt[idx] = f2bf(w[(long long)k * Ncols + nn]);
}

// ================= CSR build =================
__global__ void count_kernel(const int* __restrict__ dst, int* __restrict__ cnt, int E) {
    int e = blockIdx.x * blockDim.x + threadIdx.x;
    if (e < E) atomicAdd(&cnt[dst[e]], 1);
}

__global__ void block_sums_kernel(const int* __restrict__ cnt, int* __restrict__ partial, int N) {
    __shared__ int sdata[256];
    int t = threadIdx.x;
    int base = blockIdx.x * 1024;
    int s = 0;
#pragma unroll
    for (int j = 0; j < 4; ++j) {
        int i = base + t * 4 + j;
        if (i < N) s += cnt[i];
    }
    sdata[t] = s; __syncthreads();
    for (int o = 128; o; o >>= 1) {
        if (t < o) sdata[t] += sdata[t + o];
        __syncthreads();
    }
    if (t == 0) partial[blockIdx.x] = sdata[0];
}

__global__ void scan_partials_kernel(int* __restrict__ partial, int nb) {
    __shared__ int sdata[256];
    int t = threadIdx.x;
    int v = (t < nb) ? partial[t] : 0;
    sdata[t] = v; __syncthreads();
    for (int o = 1; o < 256; o <<= 1) {
        int y = (t >= o) ? sdata[t - o] : 0;
        __syncthreads();
        sdata[t] += y;
        __syncthreads();
    }
    if (t < nb) partial[t] = sdata[t] - v;
}

__global__ void scan_block_kernel(const int* __restrict__ cnt, const int* __restrict__ partial,
                                  int* __restrict__ off, int N, int E) {
    __shared__ int sdata[256];
    int b = blockIdx.x, t = threadIdx.x;
    int base = b * 1024;
    int vals[4]; int local = 0;
#pragma unroll
    for (int j = 0; j < 4; ++j) {
        int i = base + t * 4 + j;
        vals[j] = (i < N) ? cnt[i] : 0;
        local += vals[j];
    }
    sdata[t] = local; __syncthreads();
    for (int o = 1; o < 256; o <<= 1) {
        int y = (t >= o) ? sdata[t - o] : 0;
        __syncthreads();
        sdata[t] += y;
        __syncthreads();
    }
    int run = sdata[t] - local + partial[b];
#pragma unroll
    for (int j = 0; j < 4; ++j) {
        int i = base + t * 4 + j;
        if (i < N) off[i] = run;
        run += vals[j];
    }
    if (b == 0 && t == 0) off[N] = E;
}

__global__ void init_cursor_kernel(const int* __restrict__ off, int* __restrict__ cursor, int N) {
    int i = blockIdx.x * blockDim.x + threadIdx.x;
    if (i < N) cursor[i] = off[i];
}

__global__ void fill_csr_kernel(const int* __restrict__ src, const int* __restrict__ dst,
                                int* __restrict__ cursor, int* __restrict__ csr, int E) {
    int e = blockIdx.x * blockDim.x + threadIdx.x;
    if (e < E) {
        int d = dst[e];
        int p = atomicAdd(&cursor[d], 1);
        csr[p] = src[e];
    }
}

// ================= gather-mean (bf16 in) =================
// D=256: lane covers 4 cols (short4 = 8B). Output bf16.
__global__ void gather_mean256_kernel(const unsigned short* __restrict__ p, const int* __restrict__ off,
                                      const int* __restrict__ csr, unsigned short* __restrict__ agg, int N) {
    int wid  = (int)((blockIdx.x * (long long)blockDim.x + threadIdx.x) >> 6);
    int lane = threadIdx.x & 63;
    if (wid >= N) return;
    int start = off[wid], end = off[wid + 1];
    float a0 = 0, a1 = 0, a2 = 0, a3 = 0;
    int e = start;
    for (; e + 3 < end; e += 4) {
        int s0 = csr[e], s1 = csr[e + 1], s2 = csr[e + 2], s3 = csr[e + 3];
        ushort4v v0 = *(const ushort4v*)(p + (long long)s0 * 256 + lane * 4);
        ushort4v v1 = *(const ushort4v*)(p + (long long)s1 * 256 + lane * 4);
        ushort4v v2 = *(const ushort4v*)(p + (long long)s2 * 256 + lane * 4);
        ushort4v v3 = *(const ushort4v*)(p + (long long)s3 * 256 + lane * 4);
        a0 += bf2f(v0[0]) + bf2f(v1[0]) + bf2f(v2[0]) + bf2f(v3[0]);
        a1 += bf2f(v0[1]) + bf2f(v1[1]) + bf2f(v2[1]) + bf2f(v3[1]);
        a2 += bf2f(v0[2]) + bf2f(v1[2]) + bf2f(v2[2]) + bf2f(v3[2]);
        a3 += bf2f(v0[3]) + bf2f(v1[3]) + bf2f(v2[3]) + bf2f(v3[3]);
    }
    for (; e < end; ++e) {
        int s = csr[e];
        ushort4v v = *(const ushort4v*)(p + (long long)s * 256 + lane * 4);
        a0 += bf2f(v[0]); a1 += bf2f(v[1]); a2 += bf2f(v[2]); a3 += bf2f(v[3]);
    }
    float inv = 1.0f / (float)max(end - start, 1);
    ushort4v o;
    o[0] = f2bf(a0 * inv); o[1] = f2bf(a1 * inv); o[2] = f2bf(a2 * inv); o[3] = f2bf(a3 * inv);
    *(ushort4v*)(agg + (long long)wid * 256 + lane * 4) = o;
}

// D=128: lane covers 2 cols. Output f32 (feeds final-GEMM epilogue addend).
__global__ void gather_mean128_kernel(const unsigned short* __restrict__ p, const int* __restrict__ off,
                                      const int* __restrict__ csr, float* __restrict__ agg, int N) {
    int wid  = (int)((blockIdx.x * (long long)blockDim.x + threadIdx.x) >> 6);
    int lane = threadIdx.x & 63;
    if (wid >= N) return;
    int start = off[wid], end = off[wid + 1];
    float a0 = 0, a1 = 0;
    int e = start;
    for (; e + 3 < end; e += 4) {
        int s0 = csr[e], s1 = csr[e + 1], s2 = csr[e + 2], s3 = csr[e + 3];
        ushort2v v0 = *(const ushort2v*)(p + (long long)s0 * 128 + lane * 2);
        ushort2v v1 = *(const ushort2v*)(p + (long long)s1 * 128 + lane * 2);
        ushort2v v2 = *(const ushort2v*)(p + (long long)s2 * 128 + lane * 2);
        ushort2v v3 = *(const ushort2v*)(p + (long long)s3 * 128 + lane * 2);
        a0 += bf2f(v0[0]) + bf2f(v1[0]) + bf2f(v2[0]) + bf2f(v3[0]);
        a1 += bf2f(v0[1]) + bf2f(v1[1]) + bf2f(v2[1]) + bf2f(v3[1]);
    }
    for (; e < end; ++e) {
        int s = csr[e];
        ushort2v v = *(const ushort2v*)(p + (long long)s * 128 + lane * 2);
        a0 += bf2f(v[0]); a1 += bf2f(v[1]);
    }
    float inv = 1.0f / (float)max(end - start, 1);
    *(float2*)(agg + (long long)wid * 128 + lane * 2) = make_float2(a0 * inv, a1 * inv);
}

// ================= MFMA GEMM =================
// C[M x Nc] = act( A@W (+ A2@W2) (+ addend) (+ bias) )
// A: [M][K] bf16 row-major. WT: [Nc][K] bf16 (W transposed). 128x128 tile, 4 waves 2x2,
// each wave 64x64 via 4x4 frags of v_mfma_f32_16x16x32_bf16. No LDS.
template<bool TWO, bool RELU, bool BF16OUT, bool ADDEND, bool BIAS>
__global__ __launch_bounds__(256)
void mfma_gemm_kernel(const unsigned short* __restrict__ A,  const unsigned short* __restrict__ WT,
                      const unsigned short* __restrict__ A2, const unsigned short* __restrict__ WT2,
                      const float* __restrict__ addend, const float* __restrict__ bias,
                      void* __restrict__ Cout, int M, int K, int Nc)
{
    const int tid = threadIdx.x;
    const int wid = tid >> 6, lane = tid & 63;
    const int l15 = lane & 15, lg = lane >> 4;
    const int wr = wid >> 1, wc = wid & 1;
    const int row0 = blockIdx.y * 128 + wr * 64;
    const int col0 = blockIdx.x * 128 + wc * 64;

    f32x4 acc[4][4] = {};

    long long arow[4], bcol[4];
#pragma unroll
    for (int m = 0; m < 4; ++m) {
        int r = row0 + m * 16 + l15;
        arow[m] = (long long)min(r, M - 1) * K;
    }
#pragma unroll
    for (int n = 0; n < 4; ++n)
        bcol[n] = (long long)(col0 + n * 16 + l15) * K;

    const int npass = TWO ? 2 : 1;
    for (int pass = 0; pass < npass; ++pass) {
        const unsigned short* Ap = (TWO && pass) ? A2 : A;
        const unsigned short* Wp = (TWO && pass) ? WT2 : WT;
        for (int k0 = 0; k0 < K; k0 += 32) {
            const int ko = k0 + lg * 8;
            bf16x8 af[4], bfr[4];
#pragma unroll
            for (int m = 0; m < 4; ++m)
                af[m] = *(const bf16x8*)(Ap + arow[m] + ko);
#pragma unroll
            for (int n = 0; n < 4; ++n)
                bfr[n] = *(const bf16x8*)(Wp + bcol[n] + ko);
#pragma unroll
            for (int m = 0; m < 4; ++m)
#pragma unroll
                for (int n = 0; n < 4; ++n)
                    acc[m][n] = __builtin_amdgcn_mfma_f32_16x16x32_bf16(af[m], bfr[n], acc[m][n], 0, 0, 0);
        }
    }

    // epilogue: D col = lane&15, row = 4*(lane>>4)+reg
#pragma unroll
    for (int m = 0; m < 4; ++m) {
#pragma unroll
        for (int r = 0; r < 4; ++r) {
            int grow = row0 + m * 16 + lg * 4 + r;
            if (grow >= M) continue;
#pragma unroll
            for (int n = 0; n < 4; ++n) {
                int gcol = col0 + n * 16 + l15;
                float v = acc[m][n][r];
                if (ADDEND) v += addend[(long long)grow * Nc + gcol];
                if (BIAS)   v += bias[gcol];
                if (RELU)   v = fmaxf(v, 0.f);
                if (BF16OUT) ((unsigned short*)Cout)[(long long)grow * Nc + gcol] = f2bf(v);
                else         ((float*)Cout)[(long long)grow * Nc + gcol] = v;
            }
        }
    }
}

// ================= row L2-normalize =================
__global__ void normalize_kernel(float* __restrict__ out, int N) {
    int wid  = (int)((blockIdx.x * (long long)blockDim.x + threadIdx.x) >> 6);
    int lane = threadIdx.x & 63;
    if (wid >= N) return;
    float* row = out + (long long)wid * DOUT;
    float a = row[lane], b = row[lane + 64];
    float ss = a * a + b * b;
#pragma unroll
    for (int off = 32; off; off >>= 1) ss += __shfl_xor(ss, off);
    float inv = 1.0f / fmaxf(sqrtf(ss), 1e-12f);
    row[lane] = a * inv; row[lane + 64] = b * inv;
}

extern "C" void kernel_launch(void* const* d_in, const int* in_sizes, int n_in,
                              void* d_out, int out_size, void* d_ws, size_t ws_size,
                              hipStream_t stream) {
    const float* feat     = (const float*)d_in[0];
    const int*   src      = (const int*)  d_in[1];
    const int*   dst      = (const int*)  d_in[2];
    const float* w_self1  = (const float*)d_in[3];
    const float* w_neigh1 = (const float*)d_in[4];
    const float* b1       = (const float*)d_in[5];
    const float* w_self2  = (const float*)d_in[6];
    const float* w_neigh2 = (const float*)d_in[7];
    const float* b2       = (const float*)d_in[8];
    float* out = (float*)d_out;

    const int N = in_sizes[0] / DIN;    // 100000
    const int E = in_sizes[1];          // 800000

    char* ws = (char*)d_ws;
    auto a4k = [](size_t x) { return (x + 4095) & ~(size_t)4095; };
    size_t o = 0;
    int* cnt  = (int*)(ws + o); o += a4k((size_t)N * 4);
    int* off  = (int*)(ws + o); o += a4k((size_t)(N + 1) * 4);
    int* part = (int*)(ws + o); o += a4k(1024);
    int* csr  = (int*)(ws + o); o += a4k((size_t)E * 4);
    unsigned short* ws1t = (unsigned short*)(ws + o); o += a4k((size_t)DIN * DH * 2);
    unsigned short* wn1t = (unsigned short*)(ws + o); o += a4k((size_t)DIN * DH * 2);
    unsigned short* ws2t = (unsigned short*)(ws + o); o += a4k((size_t)DH * DOUT * 2);
    unsigned short* wn2t = (unsigned short*)(ws + o); o += a4k((size_t)DH * DOUT * 2);
    unsigned short* featb = (unsigned short*)(ws + o); o += a4k((size_t)N * DIN * 2);  // reused as p2b
    unsigned short* aggb  = (unsigned short*)(ws + o); o += a4k((size_t)N * DIN * 4);  // bf16 agg, reused as f32 agg2
    unsigned short* h1b   = (unsigned short*)(ws + o); o += a4k((size_t)N * DH * 2);

    unsigned short* p2b  = featb;          // layer-2 neighbor projection, bf16 [N][128]
    float*          agg2 = (float*)aggb;   // layer-2 aggregated mean, f32 [N][128]

    const int nblk = (N + 1023) / 1024;

    // ---- converts (feat + 4 weights) ----
    long long n8 = (long long)N * DIN / 8;
    cvt_bf16_kernel<<<(int)((n8 + 255) / 256), 256, 0, stream>>>(feat, featb, n8);
    wtrans_kernel<<<(DIN * DH + 255) / 256, 256, 0, stream>>>(w_self1,  ws1t, DIN, DH);
    wtrans_kernel<<<(DIN * DH + 255) / 256, 256, 0, stream>>>(w_neigh1, wn1t, DIN, DH);
    wtrans_kernel<<<(DH * DOUT + 255) / 256, 256, 0, stream>>>(w_self2,  ws2t, DH, DOUT);
    wtrans_kernel<<<(DH * DOUT + 255) / 256, 256, 0, stream>>>(w_neigh2, wn2t, DH, DOUT);

    // ---- CSR build ----
    hipMemsetAsync(cnt, 0, (size_t)N * 4, stream);
    count_kernel<<<(E + 255) / 256, 256, 0, stream>>>(dst, cnt, E);
    block_sums_kernel<<<nblk, 256, 0, stream>>>(cnt, part, N);
    scan_partials_kernel<<<1, 256, 0, stream>>>(part, nblk);
    scan_block_kernel<<<nblk, 256, 0, stream>>>(cnt, part, off, N, E);
    init_cursor_kernel<<<(N + 255) / 256, 256, 0, stream>>>(off, cnt, N);
    fill_csr_kernel<<<(E + 255) / 256, 256, 0, stream>>>(src, dst, cnt, csr, E);

    const int mblk = (N + 127) / 128;   // 782

    // ---- layer 1 ----
    gather_mean256_kernel<<<(N + 3) / 4, 256, 0, stream>>>(featb, off, csr, aggb, N);
    mfma_gemm_kernel<true, true, true, false, true><<<dim3(DH / 128, mblk), 256, 0, stream>>>(
        featb, ws1t, aggb, wn1t, nullptr, b1, h1b, N, DIN, DH);

    // ---- layer 2 ----
    mfma_gemm_kernel<false, false, true, false, false><<<dim3(DOUT / 128, mblk), 256, 0, stream>>>(
        h1b, wn2t, nullptr, nullptr, nullptr, nullptr, p2b, N, DH, DOUT);
    gather_mean128_kernel<<<(N + 3) / 4, 256, 0, stream>>>(p2b, off, csr, agg2, N);
    mfma_gemm_kernel<false, true, false, true, true><<<dim3(DOUT / 128, mblk), 256, 0, stream>>>(
        h1b, ws2t, nullptr, nullptr, agg2, b2, out, N, DH, DOUT);

    // ---- normalize ----
    normalize_kernel<<<(N + 3) / 4, 256, 0, stream>>>(out, N);
}

// Round 4
// 364.919 us; speedup vs baseline: 4.3010x; 1.2372x over previous
//
#include <hip/hip_runtime.h>

#define DIN 256
#define DH  256
#define DOUT 128

typedef __attribute__((ext_vector_type(8))) short bf16x8;
typedef __attribute__((ext_vector_type(4))) float f32x4;
typedef __attribute__((ext_vector_type(2))) unsigned short ushort2v;
typedef __attribute__((ext_vector_type(4))) unsigned short ushort4v;
typedef __attribute__((ext_vector_type(8))) unsigned short ushort8v;

static __device__ __forceinline__ unsigned short f2bf(float x) {
    unsigned u = __float_as_uint(x);
    u += 0x7fffu + ((u >> 16) & 1u);          // round-to-nearest-even
    return (unsigned short)(u >> 16);
}
static __device__ __forceinline__ float bf2f(unsigned short h) {
    return __uint_as_float(((unsigned)h) << 16);
}

static __device__ __forceinline__ void gload16(const unsigned short* g, void* l) {
    __builtin_amdgcn_global_load_lds(
        (const __attribute__((address_space(1))) unsigned int*)g,
        (__attribute__((address_space(3))) unsigned int*)l,
        16, 0, 0);
}

// ================= converts =================
__global__ void cvt_bf16_kernel(const float* __restrict__ x, unsigned short* __restrict__ y, long long n8) {
    long long i = blockIdx.x * 256LL + threadIdx.x;
    if (i >= n8) return;
    const float4* p = (const float4*)(x + i * 8);
    float4 a = p[0], b = p[1];
    ushort8v o;
    o[0] = f2bf(a.x); o[1] = f2bf(a.y); o[2] = f2bf(a.z); o[3] = f2bf(a.w);
    o[4] = f2bf(b.x); o[5] = f2bf(b.y); o[6] = f2bf(b.z); o[7] = f2bf(b.w);
    *(ushort8v*)(y + i * 8) = o;
}

// wt[n][k] = bf16(w[k][n])
__global__ void wtrans_kernel(const float* __restrict__ w, unsigned short* __restrict__ wt, int K, int Ncols) {
    int idx = blockIdx.x * 256 + threadIdx.x;
    if (idx >= K * Ncols) return;
    int nn = idx / K, k = idx - nn * K;
    wt[idx] = f2bf(w[(long long)k * Ncols + nn]);
}

// ================= CSR build =================
__global__ void count_kernel(const int* __restrict__ dst, int* __restrict__ cnt, int E) {
    int e = blockIdx.x * blockDim.x + threadIdx.x;
    if (e < E) atomicAdd(&cnt[dst[e]], 1);
}

__global__ void block_sums_kernel(const int* __restrict__ cnt, int* __restrict__ partial, int N) {
    __shared__ int sdata[256];
    int t = threadIdx.x;
    int base = blockIdx.x * 1024;
    int s = 0;
#pragma unroll
    for (int j = 0; j < 4; ++j) {
        int i = base + t * 4 + j;
        if (i < N) s += cnt[i];
    }
    sdata[t] = s; __syncthreads();
    for (int o = 128; o; o >>= 1) {
        if (t < o) sdata[t] += sdata[t + o];
        __syncthreads();
    }
    if (t == 0) partial[blockIdx.x] = sdata[0];
}

__global__ void scan_partials_kernel(int* __restrict__ partial, int nb) {
    __shared__ int sdata[256];
    int t = threadIdx.x;
    int v = (t < nb) ? partial[t] : 0;
    sdata[t] = v; __syncthreads();
    for (int o = 1; o < 256; o <<= 1) {
        int y = (t >= o) ? sdata[t - o] : 0;
        __syncthreads();
        sdata[t] += y;
        __syncthreads();
    }
    if (t < nb) partial[t] = sdata[t] - v;
}

__global__ void scan_block_kernel(const int* __restrict__ cnt, const int* __restrict__ partial,
                                  int* __restrict__ off, int N, int E) {
    __shared__ int sdata[256];
    int b = blockIdx.x, t = threadIdx.x;
    int base = b * 1024;
    int vals[4]; int local = 0;
#pragma unroll
    for (int j = 0; j < 4; ++j) {
        int i = base + t * 4 + j;
        vals[j] = (i < N) ? cnt[i] : 0;
        local += vals[j];
    }
    sdata[t] = local; __syncthreads();
    for (int o = 1; o < 256; o <<= 1) {
        int y = (t >= o) ? sdata[t - o] : 0;
        __syncthreads();
        sdata[t] += y;
        __syncthreads();
    }
    int run = sdata[t] - local + partial[b];
#pragma unroll
    for (int j = 0; j < 4; ++j) {
        int i = base + t * 4 + j;
        if (i < N) off[i] = run;
        run += vals[j];
    }
    if (b == 0 && t == 0) off[N] = E;
}

__global__ void init_cursor_kernel(const int* __restrict__ off, int* __restrict__ cursor, int N) {
    int i = blockIdx.x * blockDim.x + threadIdx.x;
    if (i < N) cursor[i] = off[i];
}

__global__ void fill_csr_kernel(const int* __restrict__ src, const int* __restrict__ dst,
                                int* __restrict__ cursor, int* __restrict__ csr, int E) {
    int e = blockIdx.x * blockDim.x + threadIdx.x;
    if (e < E) {
        int d = dst[e];
        int p = atomicAdd(&cursor[d], 1);
        csr[p] = src[e];
    }
}

// ================= gather-mean (bf16 in) =================
__global__ void gather_mean256_kernel(const unsigned short* __restrict__ p, const int* __restrict__ off,
                                      const int* __restrict__ csr, unsigned short* __restrict__ agg, int N) {
    int wid  = (int)((blockIdx.x * (long long)blockDim.x + threadIdx.x) >> 6);
    int lane = threadIdx.x & 63;
    if (wid >= N) return;
    int start = off[wid], end = off[wid + 1];
    float a0 = 0, a1 = 0, a2 = 0, a3 = 0;
    int e = start;
    for (; e + 3 < end; e += 4) {
        int s0 = csr[e], s1 = csr[e + 1], s2 = csr[e + 2], s3 = csr[e + 3];
        ushort4v v0 = *(const ushort4v*)(p + (long long)s0 * 256 + lane * 4);
        ushort4v v1 = *(const ushort4v*)(p + (long long)s1 * 256 + lane * 4);
        ushort4v v2 = *(const ushort4v*)(p + (long long)s2 * 256 + lane * 4);
        ushort4v v3 = *(const ushort4v*)(p + (long long)s3 * 256 + lane * 4);
        a0 += bf2f(v0[0]) + bf2f(v1[0]) + bf2f(v2[0]) + bf2f(v3[0]);
        a1 += bf2f(v0[1]) + bf2f(v1[1]) + bf2f(v2[1]) + bf2f(v3[1]);
        a2 += bf2f(v0[2]) + bf2f(v1[2]) + bf2f(v2[2]) + bf2f(v3[2]);
        a3 += bf2f(v0[3]) + bf2f(v1[3]) + bf2f(v2[3]) + bf2f(v3[3]);
    }
    for (; e < end; ++e) {
        int s = csr[e];
        ushort4v v = *(const ushort4v*)(p + (long long)s * 256 + lane * 4);
        a0 += bf2f(v[0]); a1 += bf2f(v[1]); a2 += bf2f(v[2]); a3 += bf2f(v[3]);
    }
    float inv = 1.0f / (float)max(end - start, 1);
    ushort4v o;
    o[0] = f2bf(a0 * inv); o[1] = f2bf(a1 * inv); o[2] = f2bf(a2 * inv); o[3] = f2bf(a3 * inv);
    *(ushort4v*)(agg + (long long)wid * 256 + lane * 4) = o;
}

__global__ void gather_mean128_kernel(const unsigned short* __restrict__ p, const int* __restrict__ off,
                                      const int* __restrict__ csr, float* __restrict__ agg, int N) {
    int wid  = (int)((blockIdx.x * (long long)blockDim.x + threadIdx.x) >> 6);
    int lane = threadIdx.x & 63;
    if (wid >= N) return;
    int start = off[wid], end = off[wid + 1];
    float a0 = 0, a1 = 0;
    int e = start;
    for (; e + 3 < end; e += 4) {
        int s0 = csr[e], s1 = csr[e + 1], s2 = csr[e + 2], s3 = csr[e + 3];
        ushort2v v0 = *(const ushort2v*)(p + (long long)s0 * 128 + lane * 2);
        ushort2v v1 = *(const ushort2v*)(p + (long long)s1 * 128 + lane * 2);
        ushort2v v2 = *(const ushort2v*)(p + (long long)s2 * 128 + lane * 2);
        ushort2v v3 = *(const ushort2v*)(p + (long long)s3 * 128 + lane * 2);
        a0 += bf2f(v0[0]) + bf2f(v1[0]) + bf2f(v2[0]) + bf2f(v3[0]);
        a1 += bf2f(v0[1]) + bf2f(v1[1]) + bf2f(v2[1]) + bf2f(v3[1]);
    }
    for (; e < end; ++e) {
        int s = csr[e];
        ushort2v v = *(const ushort2v*)(p + (long long)s * 128 + lane * 2);
        a0 += bf2f(v[0]); a1 += bf2f(v[1]);
    }
    float inv = 1.0f / (float)max(end - start, 1);
    *(float2*)(agg + (long long)wid * 128 + lane * 2) = make_float2(a0 * inv, a1 * inv);
}

// ================= MFMA GEMM (LDS double-buffered, m97 structure) =================
// C[M x Nc] = act( A@W (+ A2@W2) (+ addend) (+ bias) )
// A: [M][K] bf16 row-major. WT: [Nc][K] bf16. Tile 128x128, BK=32, 4 waves 2x2.
// LDS: 2 bufs x (A 8KB + B 8KB) staged via global_load_lds(16B), linear dest,
// k-chunk pre-swizzled at the SOURCE (s ^= r&3) and un-swizzled on ds_read.
template<bool TWO, bool RELU, bool BF16OUT, bool ADDEND, bool BIAS>
__global__ __launch_bounds__(256)
void mfma_gemm_kernel(const unsigned short* __restrict__ A,  const unsigned short* __restrict__ WT,
                      const unsigned short* __restrict__ A2, const unsigned short* __restrict__ WT2,
                      const float* __restrict__ addend, const float* __restrict__ bias,
                      void* __restrict__ Cout, int M, int K, int Nc)
{
    __shared__ __align__(16) char lds[2][2][8192];

    const int tid  = threadIdx.x;
    const int wid  = tid >> 6, lane = tid & 63;
    const int l15  = lane & 15, lg = lane >> 4;
    const int wr   = wid >> 1,  wc = wid & 1;
    const int row0 = blockIdx.y * 128;
    const int col0 = blockIdx.x * 128;

    // ---- staging geometry (step-invariant) ----
    // chunk c = wid*128 + i*64 + lane; r = c>>2; s = c&3; source k-chunk = s^(r&3)
    long long asrc[2], bsrc[2];
    int ldst[2];
#pragma unroll
    for (int i = 0; i < 2; ++i) {
        int c = wid * 128 + i * 64 + lane;
        int r = c >> 2, s = c & 3;
        int kc = s ^ (r & 3);
        asrc[i] = (long long)min(row0 + r, M - 1) * K + kc * 8;
        bsrc[i] = (long long)min(col0 + r, Nc - 1) * K + kc * 8;
        ldst[i] = (wid * 128 + i * 64) * 16;   // uniform per wave
    }

    // ---- fragment ds_read offsets (step-invariant) ----
    const int slotb = (lg ^ (l15 & 3)) * 16;
    int aoff[4], boff[4];
#pragma unroll
    for (int m = 0; m < 4; ++m) {
        aoff[m] = (wr * 64 + m * 16 + l15) * 64 + slotb;
        boff[m] = (wc * 64 + m * 16 + l15) * 64 + slotb;
    }

    const int ksteps = K / 32;
    const int nt = (TWO ? 2 : 1) * ksteps;

    f32x4 acc[4][4] = {};

    auto stage = [&](int buf, int t) {
        const unsigned short* Ap = (TWO && t >= ksteps) ? A2 : A;
        const unsigned short* Wp = (TWO && t >= ksteps) ? WT2 : WT;
        int k0 = (t >= ksteps ? t - ksteps : t) * 32;
#pragma unroll
        for (int i = 0; i < 2; ++i) {
            gload16(Ap + asrc[i] + k0, &lds[buf][0][ldst[i]]);
            gload16(Wp + bsrc[i] + k0, &lds[buf][1][ldst[i]]);
        }
    };

    stage(0, 0);
    __syncthreads();    // drains vmcnt -> tile 0 visible

    for (int t = 0; t < nt; ++t) {
        const int cur = t & 1;
        if (t + 1 < nt) stage(cur ^ 1, t + 1);   // prefetch next tile
        const char* As = lds[cur][0];
        const char* Bs = lds[cur][1];
        bf16x8 af[4], bfr[4];
#pragma unroll
        for (int m = 0; m < 4; ++m) af[m]  = *(const bf16x8*)(As + aoff[m]);
#pragma unroll
        for (int n = 0; n < 4; ++n) bfr[n] = *(const bf16x8*)(Bs + boff[n]);
#pragma unroll
        for (int m = 0; m < 4; ++m)
#pragma unroll
            for (int n = 0; n < 4; ++n)
                acc[m][n] = __builtin_amdgcn_mfma_f32_16x16x32_bf16(af[m], bfr[n], acc[m][n], 0, 0, 0);
        __syncthreads();   // drains prefetch vmcnt + protects buffer reuse
    }

    // ---- epilogue: D col = lane&15, row = 4*(lane>>4)+reg ----
#pragma unroll
    for (int m = 0; m < 4; ++m) {
#pragma unroll
        for (int rr = 0; rr < 4; ++rr) {
            int grow = row0 + wr * 64 + m * 16 + lg * 4 + rr;
            if (grow >= M) continue;
#pragma unroll
            for (int n = 0; n < 4; ++n) {
                int gcol = col0 + wc * 64 + n * 16 + l15;
                float v = acc[m][n][rr];
                if (ADDEND) v += addend[(long long)grow * Nc + gcol];
                if (BIAS)   v += bias[gcol];
                if (RELU)   v = fmaxf(v, 0.f);
                if (BF16OUT) ((unsigned short*)Cout)[(long long)grow * Nc + gcol] = f2bf(v);
                else         ((float*)Cout)[(long long)grow * Nc + gcol] = v;
            }
        }
    }
}

// ================= row L2-normalize =================
__global__ void normalize_kernel(float* __restrict__ out, int N) {
    int wid  = (int)((blockIdx.x * (long long)blockDim.x + threadIdx.x) >> 6);
    int lane = threadIdx.x & 63;
    if (wid >= N) return;
    float* row = out + (long long)wid * DOUT;
    float a = row[lane], b = row[lane + 64];
    float ss = a * a + b * b;
#pragma unroll
    for (int off = 32; off; off >>= 1) ss += __shfl_xor(ss, off);
    float inv = 1.0f / fmaxf(sqrtf(ss), 1e-12f);
    row[lane] = a * inv; row[lane + 64] = b * inv;
}

extern "C" void kernel_launch(void* const* d_in, const int* in_sizes, int n_in,
                              void* d_out, int out_size, void* d_ws, size_t ws_size,
                              hipStream_t stream) {
    const float* feat     = (const float*)d_in[0];
    const int*   src      = (const int*)  d_in[1];
    const int*   dst      = (const int*)  d_in[2];
    const float* w_self1  = (const float*)d_in[3];
    const float* w_neigh1 = (const float*)d_in[4];
    const float* b1       = (const float*)d_in[5];
    const float* w_self2  = (const float*)d_in[6];
    const float* w_neigh2 = (const float*)d_in[7];
    const float* b2       = (const float*)d_in[8];
    float* out = (float*)d_out;

    const int N = in_sizes[0] / DIN;    // 100000
    const int E = in_sizes[1];          // 800000

    char* ws = (char*)d_ws;
    auto a4k = [](size_t x) { return (x + 4095) & ~(size_t)4095; };
    size_t o = 0;
    int* cnt  = (int*)(ws + o); o += a4k((size_t)N * 4);
    int* off  = (int*)(ws + o); o += a4k((size_t)(N + 1) * 4);
    int* part = (int*)(ws + o); o += a4k(1024);
    int* csr  = (int*)(ws + o); o += a4k((size_t)E * 4);
    unsigned short* ws1t = (unsigned short*)(ws + o); o += a4k((size_t)DIN * DH * 2);
    unsigned short* wn1t = (unsigned short*)(ws + o); o += a4k((size_t)DIN * DH * 2);
    unsigned short* ws2t = (unsigned short*)(ws + o); o += a4k((size_t)DH * DOUT * 2);
    unsigned short* wn2t = (unsigned short*)(ws + o); o += a4k((size_t)DH * DOUT * 2);
    unsigned short* featb = (unsigned short*)(ws + o); o += a4k((size_t)N * DIN * 2);  // reused as p2b
    unsigned short* aggb  = (unsigned short*)(ws + o); o += a4k((size_t)N * DIN * 4);  // bf16 agg, reused as f32 agg2
    unsigned short* h1b   = (unsigned short*)(ws + o); o += a4k((size_t)N * DH * 2);

    unsigned short* p2b  = featb;          // layer-2 neighbor projection, bf16 [N][128]
    float*          agg2 = (float*)aggb;   // layer-2 aggregated mean, f32 [N][128]

    const int nblk = (N + 1023) / 1024;

    // ---- converts (feat + 4 weights) ----
    long long n8 = (long long)N * DIN / 8;
    cvt_bf16_kernel<<<(int)((n8 + 255) / 256), 256, 0, stream>>>(feat, featb, n8);
    wtrans_kernel<<<(DIN * DH + 255) / 256, 256, 0, stream>>>(w_self1,  ws1t, DIN, DH);
    wtrans_kernel<<<(DIN * DH + 255) / 256, 256, 0, stream>>>(w_neigh1, wn1t, DIN, DH);
    wtrans_kernel<<<(DH * DOUT + 255) / 256, 256, 0, stream>>>(w_self2,  ws2t, DH, DOUT);
    wtrans_kernel<<<(DH * DOUT + 255) / 256, 256, 0, stream>>>(w_neigh2, wn2t, DH, DOUT);

    // ---- CSR build ----
    hipMemsetAsync(cnt, 0, (size_t)N * 4, stream);
    count_kernel<<<(E + 255) / 256, 256, 0, stream>>>(dst, cnt, E);
    block_sums_kernel<<<nblk, 256, 0, stream>>>(cnt, part, N);
    scan_partials_kernel<<<1, 256, 0, stream>>>(part, nblk);
    scan_block_kernel<<<nblk, 256, 0, stream>>>(cnt, part, off, N, E);
    init_cursor_kernel<<<(N + 255) / 256, 256, 0, stream>>>(off, cnt, N);
    fill_csr_kernel<<<(E + 255) / 256, 256, 0, stream>>>(src, dst, cnt, csr, E);

    const int mblk = (N + 127) / 128;   // 782

    // ---- layer 1 ----
    gather_mean256_kernel<<<(N + 3) / 4, 256, 0, stream>>>(featb, off, csr, aggb, N);
    mfma_gemm_kernel<true, true, true, false, true><<<dim3(DH / 128, mblk), 256, 0, stream>>>(
        featb, ws1t, aggb, wn1t, nullptr, b1, h1b, N, DIN, DH);

    // ---- layer 2 ----
    mfma_gemm_kernel<false, false, true, false, false><<<dim3(DOUT / 128, mblk), 256, 0, stream>>>(
        h1b, wn2t, nullptr, nullptr, nullptr, nullptr, p2b, N, DH, DOUT);
    gather_mean128_kernel<<<(N + 3) / 4, 256, 0, stream>>>(p2b, off, csr, agg2, N);
    mfma_gemm_kernel<false, true, false, true, true><<<dim3(DOUT / 128, mblk), 256, 0, stream>>>(
        h1b, ws2t, nullptr, nullptr, agg2, b2, out, N, DH, DOUT);

    // ---- normalize ----
    normalize_kernel<<<(N + 3) / 4, 256, 0, stream>>>(out, N);
}

// Round 5
// 330.588 us; speedup vs baseline: 4.7476x; 1.1038x over previous
//
#include <hip/hip_runtime.h>

#define DIN 256
#define DH  256
#define DOUT 128

typedef __attribute__((ext_vector_type(8))) short bf16x8;
typedef __attribute__((ext_vector_type(4))) float f32x4;
typedef __attribute__((ext_vector_type(2))) unsigned short ushort2v;
typedef __attribute__((ext_vector_type(4))) unsigned short ushort4v;
typedef __attribute__((ext_vector_type(8))) unsigned short ushort8v;

static __device__ __forceinline__ unsigned short f2bf(float x) {
    unsigned u = __float_as_uint(x);
    u += 0x7fffu + ((u >> 16) & 1u);          // round-to-nearest-even
    return (unsigned short)(u >> 16);
}
static __device__ __forceinline__ float bf2f(unsigned short h) {
    return __uint_as_float(((unsigned)h) << 16);
}

static __device__ __forceinline__ void gload16(const unsigned short* g, void* l) {
    __builtin_amdgcn_global_load_lds(
        (const __attribute__((address_space(1))) unsigned int*)g,
        (__attribute__((address_space(3))) unsigned int*)l,
        16, 0, 0);
}

// ================= converts =================
__global__ void cvt_bf16_kernel(const float* __restrict__ x, unsigned short* __restrict__ y, long long n8) {
    long long i = blockIdx.x * 256LL + threadIdx.x;
    if (i >= n8) return;
    const float4* p = (const float4*)(x + i * 8);
    float4 a = p[0], b = p[1];
    ushort8v o;
    o[0] = f2bf(a.x); o[1] = f2bf(a.y); o[2] = f2bf(a.z); o[3] = f2bf(a.w);
    o[4] = f2bf(b.x); o[5] = f2bf(b.y); o[6] = f2bf(b.z); o[7] = f2bf(b.w);
    *(ushort8v*)(y + i * 8) = o;
}

// all 4 weight transposes in one launch: wt[n][k] = bf16(w[k][n])
__global__ void wtrans_all_kernel(const float* __restrict__ w_self1, const float* __restrict__ w_neigh1,
                                  const float* __restrict__ w_self2, const float* __restrict__ w_neigh2,
                                  unsigned short* __restrict__ ws1t, unsigned short* __restrict__ wn1t,
                                  unsigned short* __restrict__ ws2t, unsigned short* __restrict__ wn2t) {
    int idx = blockIdx.x * 256 + threadIdx.x;
    if (idx < 65536) {
        int nn = idx >> 8, k = idx & 255;
        ws1t[idx] = f2bf(w_self1[k * 256 + nn]);
    } else if (idx < 131072) {
        int j = idx - 65536; int nn = j >> 8, k = j & 255;
        wn1t[j] = f2bf(w_neigh1[k * 256 + nn]);
    } else if (idx < 163840) {
        int j = idx - 131072; int nn = j >> 8, k = j & 255;
        ws2t[j] = f2bf(w_self2[k * 128 + nn]);
    } else if (idx < 196608) {
        int j = idx - 163840; int nn = j >> 8, k = j & 255;
        wn2t[j] = f2bf(w_neigh2[k * 128 + nn]);
    }
}

// ================= CSR build =================
__global__ void count_kernel(const int* __restrict__ dst, int* __restrict__ cnt, int E) {
    int e = blockIdx.x * blockDim.x + threadIdx.x;
    if (e < E) atomicAdd(&cnt[dst[e]], 1);
}

__global__ void block_sums_kernel(const int* __restrict__ cnt, int* __restrict__ partial, int N) {
    __shared__ int sdata[256];
    int t = threadIdx.x;
    int base = blockIdx.x * 1024;
    int s = 0;
#pragma unroll
    for (int j = 0; j < 4; ++j) {
        int i = base + t * 4 + j;
        if (i < N) s += cnt[i];
    }
    sdata[t] = s; __syncthreads();
    for (int o = 128; o; o >>= 1) {
        if (t < o) sdata[t] += sdata[t + o];
        __syncthreads();
    }
    if (t == 0) partial[blockIdx.x] = sdata[0];
}

__global__ void scan_partials_kernel(int* __restrict__ partial, int nb) {
    __shared__ int sdata[256];
    int t = threadIdx.x;
    int v = (t < nb) ? partial[t] : 0;
    sdata[t] = v; __syncthreads();
    for (int o = 1; o < 256; o <<= 1) {
        int y = (t >= o) ? sdata[t - o] : 0;
        __syncthreads();
        sdata[t] += y;
        __syncthreads();
    }
    if (t < nb) partial[t] = sdata[t] - v;
}

// writes offsets AND initializes the fill-cursor (same values)
__global__ void scan_block_kernel(int* __restrict__ cnt, const int* __restrict__ partial,
                                  int* __restrict__ off, int N, int E) {
    __shared__ int sdata[256];
    int b = blockIdx.x, t = threadIdx.x;
    int base = b * 1024;
    int vals[4]; int local = 0;
#pragma unroll
    for (int j = 0; j < 4; ++j) {
        int i = base + t * 4 + j;
        vals[j] = (i < N) ? cnt[i] : 0;
        local += vals[j];
    }
    sdata[t] = local; __syncthreads();
    for (int o = 1; o < 256; o <<= 1) {
        int y = (t >= o) ? sdata[t - o] : 0;
        __syncthreads();
        sdata[t] += y;
        __syncthreads();
    }
    int run = sdata[t] - local + partial[b];
#pragma unroll
    for (int j = 0; j < 4; ++j) {
        int i = base + t * 4 + j;
        if (i < N) { off[i] = run; cnt[i] = run; }   // cnt becomes cursor
        run += vals[j];
    }
    if (b == 0 && t == 0) off[N] = E;
}

__global__ void fill_csr_kernel(const int* __restrict__ src, const int* __restrict__ dst,
                                int* __restrict__ cursor, int* __restrict__ csr, int E) {
    int e = blockIdx.x * blockDim.x + threadIdx.x;
    if (e < E) {
        int d = dst[e];
        int p = atomicAdd(&cursor[d], 1);
        csr[p] = src[e];
    }
}

// ================= gather-mean (bf16 in) =================
__global__ void gather_mean256_kernel(const unsigned short* __restrict__ p, const int* __restrict__ off,
                                      const int* __restrict__ csr, unsigned short* __restrict__ agg, int N) {
    int wid  = (int)((blockIdx.x * (long long)blockDim.x + threadIdx.x) >> 6);
    int lane = threadIdx.x & 63;
    if (wid >= N) return;
    int start = off[wid], end = off[wid + 1];
    float a0 = 0, a1 = 0, a2 = 0, a3 = 0;
    int e = start;
    for (; e + 3 < end; e += 4) {
        int s0 = csr[e], s1 = csr[e + 1], s2 = csr[e + 2], s3 = csr[e + 3];
        ushort4v v0 = *(const ushort4v*)(p + (long long)s0 * 256 + lane * 4);
        ushort4v v1 = *(const ushort4v*)(p + (long long)s1 * 256 + lane * 4);
        ushort4v v2 = *(const ushort4v*)(p + (long long)s2 * 256 + lane * 4);
        ushort4v v3 = *(const ushort4v*)(p + (long long)s3 * 256 + lane * 4);
        a0 += bf2f(v0[0]) + bf2f(v1[0]) + bf2f(v2[0]) + bf2f(v3[0]);
        a1 += bf2f(v0[1]) + bf2f(v1[1]) + bf2f(v2[1]) + bf2f(v3[1]);
        a2 += bf2f(v0[2]) + bf2f(v1[2]) + bf2f(v2[2]) + bf2f(v3[2]);
        a3 += bf2f(v0[3]) + bf2f(v1[3]) + bf2f(v2[3]) + bf2f(v3[3]);
    }
    for (; e < end; ++e) {
        int s = csr[e];
        ushort4v v = *(const ushort4v*)(p + (long long)s * 256 + lane * 4);
        a0 += bf2f(v[0]); a1 += bf2f(v[1]); a2 += bf2f(v[2]); a3 += bf2f(v[3]);
    }
    float inv = 1.0f / (float)max(end - start, 1);
    ushort4v o;
    o[0] = f2bf(a0 * inv); o[1] = f2bf(a1 * inv); o[2] = f2bf(a2 * inv); o[3] = f2bf(a3 * inv);
    *(ushort4v*)(agg + (long long)wid * 256 + lane * 4) = o;
}

__global__ void gather_mean128_kernel(const unsigned short* __restrict__ p, const int* __restrict__ off,
                                      const int* __restrict__ csr, unsigned short* __restrict__ agg, int N) {
    int wid  = (int)((blockIdx.x * (long long)blockDim.x + threadIdx.x) >> 6);
    int lane = threadIdx.x & 63;
    if (wid >= N) return;
    int start = off[wid], end = off[wid + 1];
    float a0 = 0, a1 = 0;
    int e = start;
    for (; e + 3 < end; e += 4) {
        int s0 = csr[e], s1 = csr[e + 1], s2 = csr[e + 2], s3 = csr[e + 3];
        ushort2v v0 = *(const ushort2v*)(p + (long long)s0 * 128 + lane * 2);
        ushort2v v1 = *(const ushort2v*)(p + (long long)s1 * 128 + lane * 2);
        ushort2v v2 = *(const ushort2v*)(p + (long long)s2 * 128 + lane * 2);
        ushort2v v3 = *(const ushort2v*)(p + (long long)s3 * 128 + lane * 2);
        a0 += bf2f(v0[0]) + bf2f(v1[0]) + bf2f(v2[0]) + bf2f(v3[0]);
        a1 += bf2f(v0[1]) + bf2f(v1[1]) + bf2f(v2[1]) + bf2f(v3[1]);
    }
    for (; e < end; ++e) {
        int s = csr[e];
        ushort2v v = *(const ushort2v*)(p + (long long)s * 128 + lane * 2);
        a0 += bf2f(v[0]); a1 += bf2f(v[1]);
    }
    float inv = 1.0f / (float)max(end - start, 1);
    ushort2v o;
    o[0] = f2bf(a0 * inv); o[1] = f2bf(a1 * inv);
    *(ushort2v*)(agg + (long long)wid * 128 + lane * 2) = o;
}

// ================= GEMM 1: h1 = relu(feat@Ws1 + agg@Wn1 + b1) =================
// tile 128 rows x 256 cols (all of DH), 8 waves (2 row x 4 col), BK=32, two A-passes.
// LDS linear dest; k-chunk pre-swizzled at source (s ^ ((r>>1)&3)), un-swizzled on read.
__global__ __launch_bounds__(512)
void gemm1_kernel(const unsigned short* __restrict__ A,  const unsigned short* __restrict__ WT,
                  const unsigned short* __restrict__ A2, const unsigned short* __restrict__ WT2,
                  const float* __restrict__ bias, unsigned short* __restrict__ C, int M)
{
    const int K = 256;
    __shared__ __align__(16) char lds[2][24576];   // A: [0,8192)  B: [8192,24576)

    const int tid = threadIdx.x;
    const int wid = tid >> 6, lane = tid & 63;
    const int l15 = lane & 15, lg = lane >> 4;
    const int wr = wid >> 2, wc = wid & 3;
    const int row0 = blockIdx.x * 128;

    // staging geometry
    long long asrc; int adst;
    {
        int c = tid, r = c >> 2, s = c & 3;
        int kc = s ^ ((r >> 1) & 3);
        asrc = (long long)min(row0 + r, M - 1) * K + kc * 8;
        adst = c * 16;
    }
    long long bsrc[2]; int bdst[2];
#pragma unroll
    for (int i = 0; i < 2; ++i) {
        int c = wid * 128 + i * 64 + lane, r = c >> 2, s = c & 3;
        int kc = s ^ ((r >> 1) & 3);
        bsrc[i] = (long long)r * K + kc * 8;
        bdst[i] = 8192 + c * 16;
    }

    const int slot = (lg ^ ((l15 >> 1) & 3)) * 16;
    int aoff[4], boff[4];
#pragma unroll
    for (int m = 0; m < 4; ++m) aoff[m] = (wr * 64 + m * 16 + l15) * 64 + slot;
#pragma unroll
    for (int n = 0; n < 4; ++n) boff[n] = 8192 + (wc * 64 + n * 16 + l15) * 64 + slot;

    f32x4 acc[4][4] = {};

    auto stage = [&](int buf, int t) {
        const unsigned short* Ap = (t >= 8) ? A2 : A;
        const unsigned short* Wp = (t >= 8) ? WT2 : WT;
        int k0 = (t & 7) * 32;
        gload16(Ap + asrc + k0, &lds[buf][adst]);
        gload16(Wp + bsrc[0] + k0, &lds[buf][bdst[0]]);
        gload16(Wp + bsrc[1] + k0, &lds[buf][bdst[1]]);
    };

    stage(0, 0);
    __syncthreads();

    for (int t = 0; t < 16; ++t) {
        const int cur = t & 1;
        if (t + 1 < 16) stage(cur ^ 1, t + 1);
        const char* L = lds[cur];
        bf16x8 af[4], bfr[4];
#pragma unroll
        for (int m = 0; m < 4; ++m) af[m]  = *(const bf16x8*)(L + aoff[m]);
#pragma unroll
        for (int n = 0; n < 4; ++n) bfr[n] = *(const bf16x8*)(L + boff[n]);
#pragma unroll
        for (int m = 0; m < 4; ++m)
#pragma unroll
            for (int n = 0; n < 4; ++n)
                acc[m][n] = __builtin_amdgcn_mfma_f32_16x16x32_bf16(af[m], bfr[n], acc[m][n], 0, 0, 0);
        __syncthreads();
    }

#pragma unroll
    for (int m = 0; m < 4; ++m) {
#pragma unroll
        for (int rr = 0; rr < 4; ++rr) {
            int grow = row0 + wr * 64 + m * 16 + lg * 4 + rr;
            if (grow >= M) continue;
#pragma unroll
            for (int n = 0; n < 4; ++n) {
                int gcol = wc * 64 + n * 16 + l15;
                float v = fmaxf(acc[m][n][rr] + bias[gcol], 0.f);
                C[(long long)grow * 256 + gcol] = f2bf(v);
            }
        }
    }
}

// ================= GEMM 2: p2 = h1 @ Wn2 (bf16 out, 128 cols) =================
__global__ __launch_bounds__(256)
void gemm2_kernel(const unsigned short* __restrict__ A, const unsigned short* __restrict__ WT,
                  unsigned short* __restrict__ C, int M)
{
    const int K = 256;
    __shared__ __align__(16) char lds[2][2][8192];

    const int tid = threadIdx.x;
    const int wid = tid >> 6, lane = tid & 63;
    const int l15 = lane & 15, lg = lane >> 4;
    const int wr = wid >> 1, wc = wid & 1;
    const int row0 = blockIdx.x * 128;

    long long asrc[2], bsrc[2];
    int ldst[2];
#pragma unroll
    for (int i = 0; i < 2; ++i) {
        int c = wid * 128 + i * 64 + lane, r = c >> 2, s = c & 3;
        int kc = s ^ ((r >> 1) & 3);
        asrc[i] = (long long)min(row0 + r, M - 1) * K + kc * 8;
        bsrc[i] = (long long)r * K + kc * 8;
        ldst[i] = c * 16;
    }

    const int slot = (lg ^ ((l15 >> 1) & 3)) * 16;
    int aoff[4], boff[4];
#pragma unroll
    for (int m = 0; m < 4; ++m) {
        aoff[m] = (wr * 64 + m * 16 + l15) * 64 + slot;
        boff[m] = (wc * 64 + m * 16 + l15) * 64 + slot;
    }

    f32x4 acc[4][4] = {};

    auto stage = [&](int buf, int t) {
        int k0 = t * 32;
#pragma unroll
        for (int i = 0; i < 2; ++i) {
            gload16(A  + asrc[i] + k0, &lds[buf][0][ldst[i]]);
            gload16(WT + bsrc[i] + k0, &lds[buf][1][ldst[i]]);
        }
    };

    stage(0, 0);
    __syncthreads();

    for (int t = 0; t < 8; ++t) {
        const int cur = t & 1;
        if (t + 1 < 8) stage(cur ^ 1, t + 1);
        const char* As = lds[cur][0];
        const char* Bs = lds[cur][1];
        bf16x8 af[4], bfr[4];
#pragma unroll
        for (int m = 0; m < 4; ++m) af[m]  = *(const bf16x8*)(As + aoff[m]);
#pragma unroll
        for (int n = 0; n < 4; ++n) bfr[n] = *(const bf16x8*)(Bs + boff[n]);
#pragma unroll
        for (int m = 0; m < 4; ++m)
#pragma unroll
            for (int n = 0; n < 4; ++n)
                acc[m][n] = __builtin_amdgcn_mfma_f32_16x16x32_bf16(af[m], bfr[n], acc[m][n], 0, 0, 0);
        __syncthreads();
    }

#pragma unroll
    for (int m = 0; m < 4; ++m) {
#pragma unroll
        for (int rr = 0; rr < 4; ++rr) {
            int grow = row0 + wr * 64 + m * 16 + lg * 4 + rr;
            if (grow >= M) continue;
#pragma unroll
            for (int n = 0; n < 4; ++n) {
                int gcol = wc * 64 + n * 16 + l15;
                C[(long long)grow * 128 + gcol] = f2bf(acc[m][n][rr]);
            }
        }
    }
}

// ====== GEMM 3: out = normalize(relu(h1@Ws2 + agg2 + b2)) — fused row-L2-norm ======
__global__ __launch_bounds__(256)
void gemm3_kernel(const unsigned short* __restrict__ A, const unsigned short* __restrict__ WT,
                  const unsigned short* __restrict__ addend, const float* __restrict__ bias,
                  float* __restrict__ C, int M)
{
    const int K = 256;
    __shared__ __align__(16) char lds[2][2][8192];
    __shared__ float rowss[2][128];

    const int tid = threadIdx.x;
    const int wid = tid >> 6, lane = tid & 63;
    const int l15 = lane & 15, lg = lane >> 4;
    const int wr = wid >> 1, wc = wid & 1;
    const int row0 = blockIdx.x * 128;

    long long asrc[2], bsrc[2];
    int ldst[2];
#pragma unroll
    for (int i = 0; i < 2; ++i) {
        int c = wid * 128 + i * 64 + lane, r = c >> 2, s = c & 3;
        int kc = s ^ ((r >> 1) & 3);
        asrc[i] = (long long)min(row0 + r, M - 1) * K + kc * 8;
        bsrc[i] = (long long)r * K + kc * 8;
        ldst[i] = c * 16;
    }

    const int slot = (lg ^ ((l15 >> 1) & 3)) * 16;
    int aoff[4], boff[4];
#pragma unroll
    for (int m = 0; m < 4; ++m) {
        aoff[m] = (wr * 64 + m * 16 + l15) * 64 + slot;
        boff[m] = (wc * 64 + m * 16 + l15) * 64 + slot;
    }

    f32x4 acc[4][4] = {};

    auto stage = [&](int buf, int t) {
        int k0 = t * 32;
#pragma unroll
        for (int i = 0; i < 2; ++i) {
            gload16(A  + asrc[i] + k0, &lds[buf][0][ldst[i]]);
            gload16(WT + bsrc[i] + k0, &lds[buf][1][ldst[i]]);
        }
    };

    stage(0, 0);
    __syncthreads();

    for (int t = 0; t < 8; ++t) {
        const int cur = t & 1;
        if (t + 1 < 8) stage(cur ^ 1, t + 1);
        const char* As = lds[cur][0];
        const char* Bs = lds[cur][1];
        bf16x8 af[4], bfr[4];
#pragma unroll
        for (int m = 0; m < 4; ++m) af[m]  = *(const bf16x8*)(As + aoff[m]);
#pragma unroll
        for (int n = 0; n < 4; ++n) bfr[n] = *(const bf16x8*)(Bs + boff[n]);
#pragma unroll
        for (int m = 0; m < 4; ++m)
#pragma unroll
            for (int n = 0; n < 4; ++n)
                acc[m][n] = __builtin_amdgcn_mfma_f32_16x16x32_bf16(af[m], bfr[n], acc[m][n], 0, 0, 0);
        __syncthreads();
    }

    // epilogue: v = relu(acc + addend + bias); row sum-of-squares; normalize; write f32
#pragma unroll
    for (int m = 0; m < 4; ++m) {
#pragma unroll
        for (int rr = 0; rr < 4; ++rr) {
            int rl = wr * 64 + m * 16 + lg * 4 + rr;          // local row 0..127
            long long gr = min(row0 + rl, M - 1);             // clamped for safe reads
            float ss = 0.f;
#pragma unroll
            for (int n = 0; n < 4; ++n) {
                int gcol = wc * 64 + n * 16 + l15;
                float v = acc[m][n][rr] + bf2f(addend[gr * 128 + gcol]) + bias[gcol];
                v = fmaxf(v, 0.f);
                acc[m][n][rr] = v;
                ss += v * v;
            }
            ss += __shfl_xor(ss, 1);
            ss += __shfl_xor(ss, 2);
            ss += __shfl_xor(ss, 4);
            ss += __shfl_xor(ss, 8);
            if (l15 == 0) rowss[wc][rl] = ss;
        }
    }
    __syncthreads();

#pragma unroll
    for (int m = 0; m < 4; ++m) {
#pragma unroll
        for (int rr = 0; rr < 4; ++rr) {
            int rl = wr * 64 + m * 16 + lg * 4 + rr;
            int grow = row0 + rl;
            if (grow >= M) continue;
            float tot = rowss[0][rl] + rowss[1][rl];
            float inv = 1.0f / fmaxf(sqrtf(tot), 1e-12f);
#pragma unroll
            for (int n = 0; n < 4; ++n) {
                int gcol = wc * 64 + n * 16 + l15;
                C[(long long)grow * 128 + gcol] = acc[m][n][rr] * inv;
            }
        }
    }
}

extern "C" void kernel_launch(void* const* d_in, const int* in_sizes, int n_in,
                              void* d_out, int out_size, void* d_ws, size_t ws_size,
                              hipStream_t stream) {
    const float* feat     = (const float*)d_in[0];
    const int*   src      = (const int*)  d_in[1];
    const int*   dst      = (const int*)  d_in[2];
    const float* w_self1  = (const float*)d_in[3];
    const float* w_neigh1 = (const float*)d_in[4];
    const float* b1       = (const float*)d_in[5];
    const float* w_self2  = (const float*)d_in[6];
    const float* w_neigh2 = (const float*)d_in[7];
    const float* b2       = (const float*)d_in[8];
    float* out = (float*)d_out;

    const int N = in_sizes[0] / DIN;    // 100000
    const int E = in_sizes[1];          // 800000

    char* ws = (char*)d_ws;
    auto a4k = [](size_t x) { return (x + 4095) & ~(size_t)4095; };
    size_t o = 0;
    int* cnt  = (int*)(ws + o); o += a4k((size_t)N * 4);
    int* off  = (int*)(ws + o); o += a4k((size_t)(N + 1) * 4);
    int* part = (int*)(ws + o); o += a4k(1024);
    int* csr  = (int*)(ws + o); o += a4k((size_t)E * 4);
    unsigned short* ws1t = (unsigned short*)(ws + o); o += a4k((size_t)DIN * DH * 2);
    unsigned short* wn1t = (unsigned short*)(ws + o); o += a4k((size_t)DIN * DH * 2);
    unsigned short* ws2t = (unsigned short*)(ws + o); o += a4k((size_t)DH * DOUT * 2);
    unsigned short* wn2t = (unsigned short*)(ws + o); o += a4k((size_t)DH * DOUT * 2);
    unsigned short* featb = (unsigned short*)(ws + o); o += a4k((size_t)N * DIN * 2);  // reused as p2b
    unsigned short* aggb  = (unsigned short*)(ws + o); o += a4k((size_t)N * DIN * 2);  // bf16 agg, reused as bf16 agg2
    unsigned short* h1b   = (unsigned short*)(ws + o); o += a4k((size_t)N * DH * 2);

    unsigned short* p2b  = featb;   // layer-2 neighbor projection, bf16 [N][128]
    unsigned short* agg2 = aggb;    // layer-2 aggregated mean, bf16 [N][128]

    const int nblk = (N + 1023) / 1024;

    // ---- converts ----
    long long n8 = (long long)N * DIN / 8;
    cvt_bf16_kernel<<<(int)((n8 + 255) / 256), 256, 0, stream>>>(feat, featb, n8);
    wtrans_all_kernel<<<768, 256, 0, stream>>>(w_self1, w_neigh1, w_self2, w_neigh2,
                                               ws1t, wn1t, ws2t, wn2t);

    // ---- CSR build ----
    hipMemsetAsync(cnt, 0, (size_t)N * 4, stream);
    count_kernel<<<(E + 255) / 256, 256, 0, stream>>>(dst, cnt, E);
    block_sums_kernel<<<nblk, 256, 0, stream>>>(cnt, part, N);
    scan_partials_kernel<<<1, 256, 0, stream>>>(part, nblk);
    scan_block_kernel<<<nblk, 256, 0, stream>>>(cnt, part, off, N, E);   // also inits cursor (cnt)
    fill_csr_kernel<<<(E + 255) / 256, 256, 0, stream>>>(src, dst, cnt, csr, E);

    const int mblk = (N + 127) / 128;   // 782

    // ---- layer 1 ----
    gather_mean256_kernel<<<(N + 3) / 4, 256, 0, stream>>>(featb, off, csr, aggb, N);
    gemm1_kernel<<<mblk, 512, 0, stream>>>(featb, ws1t, aggb, wn1t, b1, h1b, N);

    // ---- layer 2 ----
    gemm2_kernel<<<mblk, 256, 0, stream>>>(h1b, wn2t, p2b, N);
    gather_mean128_kernel<<<(N + 3) / 4, 256, 0, stream>>>(p2b, off, csr, agg2, N);
    gemm3_kernel<<<mblk, 256, 0, stream>>>(h1b, ws2t, agg2, b2, out, N);
}

// Round 6
// 330.416 us; speedup vs baseline: 4.7501x; 1.0005x over previous
//
#include <hip/hip_runtime.h>

#define DIN 256
#define DH  256
#define DOUT 128

typedef __attribute__((ext_vector_type(8))) short bf16x8;
typedef __attribute__((ext_vector_type(4))) float f32x4;
typedef __attribute__((ext_vector_type(8))) unsigned short ushort8v;

static __device__ __forceinline__ unsigned short f2bf(float x) {
    unsigned u = __float_as_uint(x);
    u += 0x7fffu + ((u >> 16) & 1u);          // round-to-nearest-even
    return (unsigned short)(u >> 16);
}
static __device__ __forceinline__ float bf2f(unsigned short h) {
    return __uint_as_float(((unsigned)h) << 16);
}

static __device__ __forceinline__ void gload16(const unsigned short* g, void* l) {
    __builtin_amdgcn_global_load_lds(
        (const __attribute__((address_space(1))) unsigned int*)g,
        (__attribute__((address_space(3))) unsigned int*)l,
        16, 0, 0);
}

// ================= prep: feat->bf16 | 4x weight transpose | degree count =================
__global__ void prep_kernel(const float* __restrict__ feat, unsigned short* __restrict__ featb, long long n8,
                            const float* __restrict__ w_self1, const float* __restrict__ w_neigh1,
                            const float* __restrict__ w_self2, const float* __restrict__ w_neigh2,
                            unsigned short* __restrict__ ws1t, unsigned short* __restrict__ wn1t,
                            unsigned short* __restrict__ ws2t, unsigned short* __restrict__ wn2t,
                            const int* __restrict__ dst, int* __restrict__ cnt, int E,
                            int bCvt, int bWt) {
    int b = blockIdx.x;
    if (b < bCvt) {
        long long i = b * 256LL + threadIdx.x;
        if (i >= n8) return;
        const f32x4* p = (const f32x4*)(feat + i * 8);
        f32x4 a = __builtin_nontemporal_load(p);
        f32x4 c = __builtin_nontemporal_load(p + 1);
        ushort8v o;
        o[0] = f2bf(a[0]); o[1] = f2bf(a[1]); o[2] = f2bf(a[2]); o[3] = f2bf(a[3]);
        o[4] = f2bf(c[0]); o[5] = f2bf(c[1]); o[6] = f2bf(c[2]); o[7] = f2bf(c[3]);
        *(ushort8v*)(featb + i * 8) = o;
    } else if (b < bCvt + bWt) {
        int idx = (b - bCvt) * 256 + threadIdx.x;
        if (idx < 65536) {
            int nn = idx >> 8, k = idx & 255;
            ws1t[idx] = f2bf(w_self1[k * 256 + nn]);
        } else if (idx < 131072) {
            int j = idx - 65536; int nn = j >> 8, k = j & 255;
            wn1t[j] = f2bf(w_neigh1[k * 256 + nn]);
        } else if (idx < 163840) {
            int j = idx - 131072; int nn = j >> 8, k = j & 255;
            ws2t[j] = f2bf(w_self2[k * 128 + nn]);
        } else if (idx < 196608) {
            int j = idx - 163840; int nn = j >> 8, k = j & 255;
            wn2t[j] = f2bf(w_neigh2[k * 128 + nn]);
        }
    } else {
        int e = (b - bCvt - bWt) * 256 + threadIdx.x;
        if (e < E) atomicAdd(&cnt[dst[e]], 1);
    }
}

// ================= CSR scan / fill =================
__global__ void block_sums_kernel(const int* __restrict__ cnt, int* __restrict__ partial, int N) {
    __shared__ int sdata[256];
    int t = threadIdx.x;
    int base = blockIdx.x * 1024;
    int s = 0;
#pragma unroll
    for (int j = 0; j < 4; ++j) {
        int i = base + t * 4 + j;
        if (i < N) s += cnt[i];
    }
    sdata[t] = s; __syncthreads();
    for (int o = 128; o; o >>= 1) {
        if (t < o) sdata[t] += sdata[t + o];
        __syncthreads();
    }
    if (t == 0) partial[blockIdx.x] = sdata[0];
}

__global__ void scan_partials_kernel(int* __restrict__ partial, int nb) {
    __shared__ int sdata[256];
    int t = threadIdx.x;
    int v = (t < nb) ? partial[t] : 0;
    sdata[t] = v; __syncthreads();
    for (int o = 1; o < 256; o <<= 1) {
        int y = (t >= o) ? sdata[t - o] : 0;
        __syncthreads();
        sdata[t] += y;
        __syncthreads();
    }
    if (t < nb) partial[t] = sdata[t] - v;
}

// writes offsets AND initializes the fill-cursor (same values)
__global__ void scan_block_kernel(int* __restrict__ cnt, const int* __restrict__ partial,
                                  int* __restrict__ off, int N, int E) {
    __shared__ int sdata[256];
    int b = blockIdx.x, t = threadIdx.x;
    int base = b * 1024;
    int vals[4]; int local = 0;
#pragma unroll
    for (int j = 0; j < 4; ++j) {
        int i = base + t * 4 + j;
        vals[j] = (i < N) ? cnt[i] : 0;
        local += vals[j];
    }
    sdata[t] = local; __syncthreads();
    for (int o = 1; o < 256; o <<= 1) {
        int y = (t >= o) ? sdata[t - o] : 0;
        __syncthreads();
        sdata[t] += y;
        __syncthreads();
    }
    int run = sdata[t] - local + partial[b];
#pragma unroll
    for (int j = 0; j < 4; ++j) {
        int i = base + t * 4 + j;
        if (i < N) { off[i] = run; cnt[i] = run; }   // cnt becomes cursor
        run += vals[j];
    }
    if (b == 0 && t == 0) off[N] = E;
}

__global__ void fill_csr_kernel(const int* __restrict__ src, const int* __restrict__ dst,
                                int* __restrict__ cursor, int* __restrict__ csr, int E) {
    int e = blockIdx.x * blockDim.x + threadIdx.x;
    if (e < E) {
        int d = dst[e];
        int p = atomicAdd(&cursor[d], 1);
        csr[p] = src[e];
    }
}

// ================= gather-mean D=256: 2 rows per load (half-wave each, 16B/lane) ======
__global__ void gather_mean256_kernel(const unsigned short* __restrict__ p, const int* __restrict__ off,
                                      const int* __restrict__ csr, unsigned short* __restrict__ agg, int N) {
    int wid  = (int)((blockIdx.x * (long long)blockDim.x + threadIdx.x) >> 6);
    int lane = threadIdx.x & 63;
    if (wid >= N) return;
    int start = off[wid], end = off[wid + 1];
    const int half = lane >> 5;          // 0/1: which row of the pair
    const int c8   = (lane & 31) * 8;    // 8 cols per lane -> 256
    float a[8] = {};
    int e = start;
    for (; e + 3 < end; e += 4) {        // 2 pairs in flight
        int s0 = csr[e + half], s1 = csr[e + 2 + half];
        ushort8v v0 = *(const ushort8v*)(p + (long long)s0 * 256 + c8);
        ushort8v v1 = *(const ushort8v*)(p + (long long)s1 * 256 + c8);
#pragma unroll
        for (int j = 0; j < 8; ++j) a[j] += bf2f(v0[j]) + bf2f(v1[j]);
    }
    for (; e < end; e += 2) {
        int idx = e + half;
        if (idx < end) {
            int s = csr[idx];
            ushort8v v = *(const ushort8v*)(p + (long long)s * 256 + c8);
#pragma unroll
            for (int j = 0; j < 8; ++j) a[j] += bf2f(v[j]);
        }
    }
#pragma unroll
    for (int j = 0; j < 8; ++j) a[j] += __shfl_xor(a[j], 32);
    if (half == 0) {
        float inv = 1.0f / (float)max(end - start, 1);
        ushort8v o;
#pragma unroll
        for (int j = 0; j < 8; ++j) o[j] = f2bf(a[j] * inv);
        __builtin_nontemporal_store(o, (ushort8v*)(agg + (long long)wid * 256 + c8));
    }
}

// ================= gather-mean D=128: 4 rows per load (16 lanes each, 16B/lane) ======
__global__ void gather_mean128_kernel(const unsigned short* __restrict__ p, const int* __restrict__ off,
                                      const int* __restrict__ csr, unsigned short* __restrict__ agg, int N) {
    int wid  = (int)((blockIdx.x * (long long)blockDim.x + threadIdx.x) >> 6);
    int lane = threadIdx.x & 63;
    if (wid >= N) return;
    int start = off[wid], end = off[wid + 1];
    const int g  = lane >> 4;            // 0..3: which row of the quad
    const int c8 = (lane & 15) * 8;      // 8 cols per lane -> 128
    float a[8] = {};
    int e = start;
    for (; e + 7 < end; e += 8) {        // 2 quads in flight
        int s0 = csr[e + g], s1 = csr[e + 4 + g];
        ushort8v v0 = *(const ushort8v*)(p + (long long)s0 * 128 + c8);
        ushort8v v1 = *(const ushort8v*)(p + (long long)s1 * 128 + c8);
#pragma unroll
        for (int j = 0; j < 8; ++j) a[j] += bf2f(v0[j]) + bf2f(v1[j]);
    }
    for (; e < end; e += 4) {
        int idx = e + g;
        if (idx < end) {
            int s = csr[idx];
            ushort8v v = *(const ushort8v*)(p + (long long)s * 128 + c8);
#pragma unroll
            for (int j = 0; j < 8; ++j) a[j] += bf2f(v[j]);
        }
    }
#pragma unroll
    for (int j = 0; j < 8; ++j) {
        a[j] += __shfl_xor(a[j], 16);
        a[j] += __shfl_xor(a[j], 32);
    }
    if (g == 0) {
        float inv = 1.0f / (float)max(end - start, 1);
        ushort8v o;
#pragma unroll
        for (int j = 0; j < 8; ++j) o[j] = f2bf(a[j] * inv);
        __builtin_nontemporal_store(o, (ushort8v*)(agg + (long long)wid * 128 + c8));
    }
}

// ================= GEMM 1: h1 = relu(feat@Ws1 + agg@Wn1 + b1) =================
__global__ __launch_bounds__(512)
void gemm1_kernel(const unsigned short* __restrict__ A,  const unsigned short* __restrict__ WT,
                  const unsigned short* __restrict__ A2, const unsigned short* __restrict__ WT2,
                  const float* __restrict__ bias, unsigned short* __restrict__ C, int M)
{
    const int K = 256;
    __shared__ __align__(16) char lds[2][24576];   // A: [0,8192)  B: [8192,24576)

    const int tid = threadIdx.x;
    const int wid = tid >> 6, lane = tid & 63;
    const int l15 = lane & 15, lg = lane >> 4;
    const int wr = wid >> 2, wc = wid & 3;
    const int row0 = blockIdx.x * 128;

    long long asrc; int adst;
    {
        int c = tid, r = c >> 2, s = c & 3;
        int kc = s ^ ((r >> 1) & 3);
        asrc = (long long)min(row0 + r, M - 1) * K + kc * 8;
        adst = c * 16;
    }
    long long bsrc[2]; int bdst[2];
#pragma unroll
    for (int i = 0; i < 2; ++i) {
        int c = wid * 128 + i * 64 + lane, r = c >> 2, s = c & 3;
        int kc = s ^ ((r >> 1) & 3);
        bsrc[i] = (long long)r * K + kc * 8;
        bdst[i] = 8192 + c * 16;
    }

    const int slot = (lg ^ ((l15 >> 1) & 3)) * 16;
    int aoff[4], boff[4];
#pragma unroll
    for (int m = 0; m < 4; ++m) aoff[m] = (wr * 64 + m * 16 + l15) * 64 + slot;
#pragma unroll
    for (int n = 0; n < 4; ++n) boff[n] = 8192 + (wc * 64 + n * 16 + l15) * 64 + slot;

    f32x4 acc[4][4] = {};

    auto stage = [&](int buf, int t) {
        const unsigned short* Ap = (t >= 8) ? A2 : A;
        const unsigned short* Wp = (t >= 8) ? WT2 : WT;
        int k0 = (t & 7) * 32;
        gload16(Ap + asrc + k0, &lds[buf][adst]);
        gload16(Wp + bsrc[0] + k0, &lds[buf][bdst[0]]);
        gload16(Wp + bsrc[1] + k0, &lds[buf][bdst[1]]);
    };

    stage(0, 0);
    __syncthreads();

    for (int t = 0; t < 16; ++t) {
        const int cur = t & 1;
        if (t + 1 < 16) stage(cur ^ 1, t + 1);
        const char* L = lds[cur];
        bf16x8 af[4], bfr[4];
#pragma unroll
        for (int m = 0; m < 4; ++m) af[m]  = *(const bf16x8*)(L + aoff[m]);
#pragma unroll
        for (int n = 0; n < 4; ++n) bfr[n] = *(const bf16x8*)(L + boff[n]);
#pragma unroll
        for (int m = 0; m < 4; ++m)
#pragma unroll
            for (int n = 0; n < 4; ++n)
                acc[m][n] = __builtin_amdgcn_mfma_f32_16x16x32_bf16(af[m], bfr[n], acc[m][n], 0, 0, 0);
        __syncthreads();
    }

#pragma unroll
    for (int m = 0; m < 4; ++m) {
#pragma unroll
        for (int rr = 0; rr < 4; ++rr) {
            int grow = row0 + wr * 64 + m * 16 + lg * 4 + rr;
            if (grow >= M) continue;
#pragma unroll
            for (int n = 0; n < 4; ++n) {
                int gcol = wc * 64 + n * 16 + l15;
                float v = fmaxf(acc[m][n][rr] + bias[gcol], 0.f);
                C[(long long)grow * 256 + gcol] = f2bf(v);
            }
        }
    }
}

// ================= GEMM 2: p2 = h1 @ Wn2 (bf16 out, 128 cols) =================
__global__ __launch_bounds__(256)
void gemm2_kernel(const unsigned short* __restrict__ A, const unsigned short* __restrict__ WT,
                  unsigned short* __restrict__ C, int M)
{
    const int K = 256;
    __shared__ __align__(16) char lds[2][2][8192];

    const int tid = threadIdx.x;
    const int wid = tid >> 6, lane = tid & 63;
    const int l15 = lane & 15, lg = lane >> 4;
    const int wr = wid >> 1, wc = wid & 1;
    const int row0 = blockIdx.x * 128;

    long long asrc[2], bsrc[2];
    int ldst[2];
#pragma unroll
    for (int i = 0; i < 2; ++i) {
        int c = wid * 128 + i * 64 + lane, r = c >> 2, s = c & 3;
        int kc = s ^ ((r >> 1) & 3);
        asrc[i] = (long long)min(row0 + r, M - 1) * K + kc * 8;
        bsrc[i] = (long long)r * K + kc * 8;
        ldst[i] = c * 16;
    }

    const int slot = (lg ^ ((l15 >> 1) & 3)) * 16;
    int aoff[4], boff[4];
#pragma unroll
    for (int m = 0; m < 4; ++m) {
        aoff[m] = (wr * 64 + m * 16 + l15) * 64 + slot;
        boff[m] = (wc * 64 + m * 16 + l15) * 64 + slot;
    }

    f32x4 acc[4][4] = {};

    auto stage = [&](int buf, int t) {
        int k0 = t * 32;
#pragma unroll
        for (int i = 0; i < 2; ++i) {
            gload16(A  + asrc[i] + k0, &lds[buf][0][ldst[i]]);
            gload16(WT + bsrc[i] + k0, &lds[buf][1][ldst[i]]);
        }
    };

    stage(0, 0);
    __syncthreads();

    for (int t = 0; t < 8; ++t) {
        const int cur = t & 1;
        if (t + 1 < 8) stage(cur ^ 1, t + 1);
        const char* As = lds[cur][0];
        const char* Bs = lds[cur][1];
        bf16x8 af[4], bfr[4];
#pragma unroll
        for (int m = 0; m < 4; ++m) af[m]  = *(const bf16x8*)(As + aoff[m]);
#pragma unroll
        for (int n = 0; n < 4; ++n) bfr[n] = *(const bf16x8*)(Bs + boff[n]);
#pragma unroll
        for (int m = 0; m < 4; ++m)
#pragma unroll
            for (int n = 0; n < 4; ++n)
                acc[m][n] = __builtin_amdgcn_mfma_f32_16x16x32_bf16(af[m], bfr[n], acc[m][n], 0, 0, 0);
        __syncthreads();
    }

#pragma unroll
    for (int m = 0; m < 4; ++m) {
#pragma unroll
        for (int rr = 0; rr < 4; ++rr) {
            int grow = row0 + wr * 64 + m * 16 + lg * 4 + rr;
            if (grow >= M) continue;
#pragma unroll
            for (int n = 0; n < 4; ++n) {
                int gcol = wc * 64 + n * 16 + l15;
                C[(long long)grow * 128 + gcol] = f2bf(acc[m][n][rr]);
            }
        }
    }
}

// ====== GEMM 3: out = normalize(relu(h1@Ws2 + agg2 + b2)) — fused row-L2-norm ======
__global__ __launch_bounds__(256)
void gemm3_kernel(const unsigned short* __restrict__ A, const unsigned short* __restrict__ WT,
                  const unsigned short* __restrict__ addend, const float* __restrict__ bias,
                  float* __restrict__ C, int M)
{
    const int K = 256;
    __shared__ __align__(16) char lds[2][2][8192];
    __shared__ float rowss[2][128];

    const int tid = threadIdx.x;
    const int wid = tid >> 6, lane = tid & 63;
    const int l15 = lane & 15, lg = lane >> 4;
    const int wr = wid >> 1, wc = wid & 1;
    const int row0 = blockIdx.x * 128;

    long long asrc[2], bsrc[2];
    int ldst[2];
#pragma unroll
    for (int i = 0; i < 2; ++i) {
        int c = wid * 128 + i * 64 + lane, r = c >> 2, s = c & 3;
        int kc = s ^ ((r >> 1) & 3);
        asrc[i] = (long long)min(row0 + r, M - 1) * K + kc * 8;
        bsrc[i] = (long long)r * K + kc * 8;
        ldst[i] = c * 16;
    }

    const int slot = (lg ^ ((l15 >> 1) & 3)) * 16;
    int aoff[4], boff[4];
#pragma unroll
    for (int m = 0; m < 4; ++m) {
        aoff[m] = (wr * 64 + m * 16 + l15) * 64 + slot;
        boff[m] = (wc * 64 + m * 16 + l15) * 64 + slot;
    }

    f32x4 acc[4][4] = {};

    auto stage = [&](int buf, int t) {
        int k0 = t * 32;
#pragma unroll
        for (int i = 0; i < 2; ++i) {
            gload16(A  + asrc[i] + k0, &lds[buf][0][ldst[i]]);
            gload16(WT + bsrc[i] + k0, &lds[buf][1][ldst[i]]);
        }
    };

    stage(0, 0);
    __syncthreads();

    for (int t = 0; t < 8; ++t) {
        const int cur = t & 1;
        if (t + 1 < 8) stage(cur ^ 1, t + 1);
        const char* As = lds[cur][0];
        const char* Bs = lds[cur][1];
        bf16x8 af[4], bfr[4];
#pragma unroll
        for (int m = 0; m < 4; ++m) af[m]  = *(const bf16x8*)(As + aoff[m]);
#pragma unroll
        for (int n = 0; n < 4; ++n) bfr[n] = *(const bf16x8*)(Bs + boff[n]);
#pragma unroll
        for (int m = 0; m < 4; ++m)
#pragma unroll
            for (int n = 0; n < 4; ++n)
                acc[m][n] = __builtin_amdgcn_mfma_f32_16x16x32_bf16(af[m], bfr[n], acc[m][n], 0, 0, 0);
        __syncthreads();
    }

    // epilogue: v = relu(acc + addend + bias); row sum-of-squares; normalize; nt-write f32
#pragma unroll
    for (int m = 0; m < 4; ++m) {
#pragma unroll
        for (int rr = 0; rr < 4; ++rr) {
            int rl = wr * 64 + m * 16 + lg * 4 + rr;          // local row 0..127
            long long gr = min(row0 + rl, M - 1);             // clamped for safe reads
            float ss = 0.f;
#pragma unroll
            for (int n = 0; n < 4; ++n) {
                int gcol = wc * 64 + n * 16 + l15;
                float v = acc[m][n][rr] + bf2f(addend[gr * 128 + gcol]) + bias[gcol];
                v = fmaxf(v, 0.f);
                acc[m][n][rr] = v;
                ss += v * v;
            }
            ss += __shfl_xor(ss, 1);
            ss += __shfl_xor(ss, 2);
            ss += __shfl_xor(ss, 4);
            ss += __shfl_xor(ss, 8);
            if (l15 == 0) rowss[wc][rl] = ss;
        }
    }
    __syncthreads();

#pragma unroll
    for (int m = 0; m < 4; ++m) {
#pragma unroll
        for (int rr = 0; rr < 4; ++rr) {
            int rl = wr * 64 + m * 16 + lg * 4 + rr;
            int grow = row0 + rl;
            if (grow >= M) continue;
            float tot = rowss[0][rl] + rowss[1][rl];
            float inv = 1.0f / fmaxf(sqrtf(tot), 1e-12f);
#pragma unroll
            for (int n = 0; n < 4; ++n) {
                int gcol = wc * 64 + n * 16 + l15;
                __builtin_nontemporal_store(acc[m][n][rr] * inv, &C[(long long)grow * 128 + gcol]);
            }
        }
    }
}

extern "C" void kernel_launch(void* const* d_in, const int* in_sizes, int n_in,
                              void* d_out, int out_size, void* d_ws, size_t ws_size,
                              hipStream_t stream) {
    const float* feat     = (const float*)d_in[0];
    const int*   src      = (const int*)  d_in[1];
    const int*   dst      = (const int*)  d_in[2];
    const float* w_self1  = (const float*)d_in[3];
    const float* w_neigh1 = (const float*)d_in[4];
    const float* b1       = (const float*)d_in[5];
    const float* w_self2  = (const float*)d_in[6];
    const float* w_neigh2 = (const float*)d_in[7];
    const float* b2       = (const float*)d_in[8];
    float* out = (float*)d_out;

    const int N = in_sizes[0] / DIN;    // 100000
    const int E = in_sizes[1];          // 800000

    char* ws = (char*)d_ws;
    auto a4k = [](size_t x) { return (x + 4095) & ~(size_t)4095; };
    size_t o = 0;
    int* cnt  = (int*)(ws + o); o += a4k((size_t)N * 4);
    int* off  = (int*)(ws + o); o += a4k((size_t)(N + 1) * 4);
    int* part = (int*)(ws + o); o += a4k(1024);
    int* csr  = (int*)(ws + o); o += a4k((size_t)E * 4);
    unsigned short* ws1t = (unsigned short*)(ws + o); o += a4k((size_t)DIN * DH * 2);
    unsigned short* wn1t = (unsigned short*)(ws + o); o += a4k((size_t)DIN * DH * 2);
    unsigned short* ws2t = (unsigned short*)(ws + o); o += a4k((size_t)DH * DOUT * 2);
    unsigned short* wn2t = (unsigned short*)(ws + o); o += a4k((size_t)DH * DOUT * 2);
    unsigned short* featb = (unsigned short*)(ws + o); o += a4k((size_t)N * DIN * 2);  // reused as p2b
    unsigned short* aggb  = (unsigned short*)(ws + o); o += a4k((size_t)N * DIN * 2);  // reused as agg2
    unsigned short* h1b   = (unsigned short*)(ws + o); o += a4k((size_t)N * DH * 2);

    unsigned short* p2b  = featb;   // layer-2 neighbor projection, bf16 [N][128]
    unsigned short* agg2 = aggb;    // layer-2 aggregated mean, bf16 [N][128]

    const int nblk = (N + 1023) / 1024;

    // ---- prep: cvt + wtrans + count (cnt must be zeroed first) ----
    hipMemsetAsync(cnt, 0, (size_t)N * 4, stream);
    long long n8 = (long long)N * DIN / 8;
    const int bCvt = (int)((n8 + 255) / 256);       // 12500
    const int bWt  = 768;
    const int bCnt = (E + 255) / 256;               // 3125
    prep_kernel<<<bCvt + bWt + bCnt, 256, 0, stream>>>(
        feat, featb, n8, w_self1, w_neigh1, w_self2, w_neigh2,
        ws1t, wn1t, ws2t, wn2t, dst, cnt, E, bCvt, bWt);

    // ---- CSR scan + fill ----
    block_sums_kernel<<<nblk, 256, 0, stream>>>(cnt, part, N);
    scan_partials_kernel<<<1, 256, 0, stream>>>(part, nblk);
    scan_block_kernel<<<nblk, 256, 0, stream>>>(cnt, part, off, N, E);   // also inits cursor (cnt)
    fill_csr_kernel<<<(E + 255) / 256, 256, 0, stream>>>(src, dst, cnt, csr, E);

    const int mblk = (N + 127) / 128;   // 782

    // ---- layer 1 ----
    gather_mean256_kernel<<<(N + 3) / 4, 256, 0, stream>>>(featb, off, csr, aggb, N);
    gemm1_kernel<<<mblk, 512, 0, stream>>>(featb, ws1t, aggb, wn1t, b1, h1b, N);

    // ---- layer 2 ----
    gemm2_kernel<<<mblk, 256, 0, stream>>>(h1b, wn2t, p2b, N);
    gather_mean128_kernel<<<(N + 3) / 4, 256, 0, stream>>>(p2b, off, csr, agg2, N);
    gemm3_kernel<<<mblk, 256, 0, stream>>>(h1b, ws2t, agg2, b2, out, N);
}